// Round 1
// baseline (627.398 us; speedup 1.0000x reference)
//
#include <hip/hip_runtime.h>
#include <hip/hip_bf16.h>
#include <math.h>

// Problem constants (GAT_66907000537778)
#define NNODES 50000
#define NEDGES 800000
#define FIN 256
#define HID 32
#define HEADS 4
#define OUTS 40
#define HIDDEN 128   // HEADS*HID

// ---------------------------------------------------------------------------
// CSR construction (grouped by dst)
// ---------------------------------------------------------------------------
__global__ void k_zero_int(int* __restrict__ p, int n) {
    int i = blockIdx.x * blockDim.x + threadIdx.x;
    if (i < n) p[i] = 0;
}

__global__ void k_hist(const int* __restrict__ dst, int* __restrict__ counts, int n) {
    int i = blockIdx.x * blockDim.x + threadIdx.x;
    if (i < n) atomicAdd(&counts[dst[i]], 1);
}

// single-block exclusive scan, 1024 threads, wave-shuffle based
__global__ __launch_bounds__(1024) void k_scan(const int* __restrict__ counts,
                                               int* __restrict__ row_ptr, int n) {
    __shared__ int wsum[16];
    __shared__ int carry_s;
    int tid = threadIdx.x;
    int lane = tid & 63, wid = tid >> 6;
    if (tid == 0) carry_s = 0;
    __syncthreads();
    for (int base = 0; base < n; base += 1024) {
        int i = base + tid;
        int v = (i < n) ? counts[i] : 0;
        int x = v;
        #pragma unroll
        for (int off = 1; off < 64; off <<= 1) {
            int t = __shfl_up(x, off);
            if (lane >= off) x += t;
        }
        if (lane == 63) wsum[wid] = x;
        __syncthreads();
        int carry = carry_s;
        int woff = 0;
        for (int w = 0; w < wid; ++w) woff += wsum[w];
        int incl = x + woff;
        if (i < n) row_ptr[i] = carry + incl - v;   // exclusive
        __syncthreads();
        if (tid == 1023) carry_s = carry + incl;
        __syncthreads();
    }
    if (tid == 0) row_ptr[n] = carry_s;
}

__global__ void k_copy_int(const int* __restrict__ a, int* __restrict__ b, int n) {
    int i = blockIdx.x * blockDim.x + threadIdx.x;
    if (i < n) b[i] = a[i];
}

__global__ void k_scatter(const int* __restrict__ src, const int* __restrict__ dst,
                          int* __restrict__ cursor, int* __restrict__ csr_src, int n) {
    int i = blockIdx.x * blockDim.x + threadIdx.x;
    if (i < n) {
        int p = atomicAdd(&cursor[dst[i]], 1);
        csr_src[p] = src[i];
    }
}

// ---------------------------------------------------------------------------
// fp32 GEMM: Z[M,128] = A[M,K] * W[K,128].  Block = 256 thr, tile 32(M)x128(N)
// ---------------------------------------------------------------------------
__global__ __launch_bounds__(256) void gemm_n128(const float* __restrict__ A,
                                                 const float* __restrict__ W,
                                                 float* __restrict__ Z, int M, int K) {
    __shared__ float Al[32][36];    // transposed A tile [k][row], pad 36 to spread banks
    __shared__ float Wl[32][128];
    int tid = threadIdx.x;
    int c  = tid & 127;
    int rg = tid >> 7;   // 0..1: which 16-row group
    int m0 = blockIdx.x * 32;
    float acc[16];
    #pragma unroll
    for (int r = 0; r < 16; ++r) acc[r] = 0.f;

    for (int k0 = 0; k0 < K; k0 += 32) {
        { // A tile load: thread -> (row = tid/8, k = (tid%8)*4), transpose into Al
            int a_r = tid >> 3, a_k = (tid & 7) << 2;
            int m = m0 + a_r;
            float4 v = make_float4(0.f, 0.f, 0.f, 0.f);
            if (m < M) v = *reinterpret_cast<const float4*>(&A[(size_t)m * K + k0 + a_k]);
            Al[a_k + 0][a_r] = v.x;
            Al[a_k + 1][a_r] = v.y;
            Al[a_k + 2][a_r] = v.z;
            Al[a_k + 3][a_r] = v.w;
        }
        { // W tile: 32x128 floats, float4 coalesced
            #pragma unroll
            for (int j = 0; j < 4; ++j) {
                int idx = tid * 4 + j * 1024;
                int kk = idx >> 7, cc = idx & 127;
                *reinterpret_cast<float4*>(&Wl[kk][cc]) =
                    *reinterpret_cast<const float4*>(&W[(size_t)(k0 + kk) * 128 + cc]);
            }
        }
        __syncthreads();
        #pragma unroll
        for (int k = 0; k < 32; ++k) {
            float wv = Wl[k][c];
            const float4* ap = reinterpret_cast<const float4*>(&Al[k][rg * 16]);
            float4 a0 = ap[0], a1 = ap[1], a2 = ap[2], a3 = ap[3];
            acc[0]  += a0.x * wv; acc[1]  += a0.y * wv; acc[2]  += a0.z * wv; acc[3]  += a0.w * wv;
            acc[4]  += a1.x * wv; acc[5]  += a1.y * wv; acc[6]  += a1.z * wv; acc[7]  += a1.w * wv;
            acc[8]  += a2.x * wv; acc[9]  += a2.y * wv; acc[10] += a2.z * wv; acc[11] += a2.w * wv;
            acc[12] += a3.x * wv; acc[13] += a3.y * wv; acc[14] += a3.z * wv; acc[15] += a3.w * wv;
        }
        __syncthreads();
    }
    #pragma unroll
    for (int r = 0; r < 16; ++r) {
        int m = m0 + rg * 16 + r;
        if (m < M) Z[(size_t)m * 128 + c] = acc[r];
    }
}

// Z[M,40] = A[M,128] * W[128,40]. One row per wave, block 256 = 4 rows.
__global__ __launch_bounds__(256) void gemm_n40(const float* __restrict__ A,
                                                const float* __restrict__ W,
                                                float* __restrict__ Z, int M) {
    __shared__ float Wl[128 * 40];
    __shared__ float rows[4][128];
    int tid = threadIdx.x;
    int wid = tid >> 6, lane = tid & 63;
    int m = blockIdx.x * 4 + wid;
    for (int j = tid; j < 128 * 40; j += 256) Wl[j] = W[j];
    if (m < M && lane < 32)
        *reinterpret_cast<float4*>(&rows[wid][lane * 4]) =
            *reinterpret_cast<const float4*>(&A[(size_t)m * 128 + lane * 4]);
    __syncthreads();
    if (m < M && lane < 40) {
        float acc = 0.f;
        #pragma unroll
        for (int k = 0; k < 128; ++k) acc += rows[wid][k] * Wl[k * 40 + lane];
        Z[(size_t)m * 40 + lane] = acc;
    }
}

// ---------------------------------------------------------------------------
// attention scores: el[n,h] = sum_f z[n,h,f]*al[h,f]; er likewise
// ---------------------------------------------------------------------------
__global__ __launch_bounds__(128) void attn_scores128(const float* __restrict__ z,
                                                      const float* __restrict__ al,
                                                      const float* __restrict__ ar,
                                                      float* __restrict__ el,
                                                      float* __restrict__ er, int n_nodes) {
    int n = blockIdx.x;
    if (n >= n_nodes) return;
    int h = threadIdx.x >> 5, f = threadIdx.x & 31;
    float zv = z[(size_t)n * 128 + h * 32 + f];
    float a = zv * al[h * 32 + f];
    float b = zv * ar[h * 32 + f];
    #pragma unroll
    for (int off = 16; off > 0; off >>= 1) {
        a += __shfl_xor(a, off);
        b += __shfl_xor(b, off);
    }
    if (f == 0) { el[n * 4 + h] = a; er[n * 4 + h] = b; }
}

__global__ __launch_bounds__(256) void attn_scores40(const float* __restrict__ z,
                                                     const float* __restrict__ al,
                                                     const float* __restrict__ ar,
                                                     float* __restrict__ el,
                                                     float* __restrict__ er, int n_nodes) {
    int tid = threadIdx.x;
    int wid = tid >> 6, lane = tid & 63;
    int n = blockIdx.x * 4 + wid;
    if (n >= n_nodes) return;
    bool act = lane < 40;
    float zv = act ? z[(size_t)n * 40 + lane] : 0.f;
    float a = act ? zv * al[lane] : 0.f;
    float b = act ? zv * ar[lane] : 0.f;
    #pragma unroll
    for (int off = 32; off > 0; off >>= 1) {
        a += __shfl_xor(a, off);
        b += __shfl_xor(b, off);
    }
    if (lane == 0) { el[n] = a; er[n] = b; }
}

// ---------------------------------------------------------------------------
// fused edge-softmax + aggregation, layers 1-2 (H=4, F=32).
// one 128-thread block per dst node; lane group of 32 per head; online softmax
// ---------------------------------------------------------------------------
__global__ __launch_bounds__(128) void gat_agg128(const float* __restrict__ z,
                                                  const float* __restrict__ el,
                                                  const float* __restrict__ er,
                                                  const int* __restrict__ row_ptr,
                                                  const int* __restrict__ csr_src,
                                                  const float* __restrict__ bias,
                                                  float* __restrict__ out, int n_nodes) {
    int n = blockIdx.x;
    if (n >= n_nodes) return;
    int h = threadIdx.x >> 5, f = threadIdx.x & 31;
    int beg = row_ptr[n], end = row_ptr[n + 1];
    float erv = er[n * 4 + h];
    float m = -3.0e38f, s = 0.f, acc = 0.f;
    for (int j = beg; j < end; ++j) {
        int sidx = csr_src[j];
        float e = el[sidx * 4 + h] + erv;
        e = (e > 0.f) ? e : 0.2f * e;
        float zv = z[(size_t)sidx * 128 + h * 32 + f];
        float mn = fmaxf(m, e);
        float scale = __expf(m - mn);
        float p = __expf(e - mn);
        s = s * scale + p;
        acc = acc * scale + p * zv;
        m = mn;
    }
    float o = (end > beg) ? acc / s : 0.f;
    o += bias[h * 32 + f];
    o = fmaxf(o, 0.f);   // relu (layers 1-2 always relu)
    out[(size_t)n * 128 + h * 32 + f] = o;
}

// layer 3: H=1, F=40, + bias + log_softmax, writes final output
__global__ __launch_bounds__(256) void gat_agg40_lsm(const float* __restrict__ z,
                                                     const float* __restrict__ el,
                                                     const float* __restrict__ er,
                                                     const int* __restrict__ row_ptr,
                                                     const int* __restrict__ csr_src,
                                                     const float* __restrict__ bias,
                                                     float* __restrict__ out, int n_nodes) {
    int tid = threadIdx.x;
    int wid = tid >> 6, lane = tid & 63;
    int n = blockIdx.x * 4 + wid;
    if (n >= n_nodes) return;
    bool act = lane < 40;
    int beg = row_ptr[n], end = row_ptr[n + 1];
    float erv = er[n];
    float m = -3.0e38f, s = 0.f, acc = 0.f;
    for (int j = beg; j < end; ++j) {
        int sidx = csr_src[j];
        float e = el[sidx] + erv;
        e = (e > 0.f) ? e : 0.2f * e;
        float zv = act ? z[(size_t)sidx * 40 + lane] : 0.f;
        float mn = fmaxf(m, e);
        float scale = __expf(m - mn);
        float p = __expf(e - mn);
        s = s * scale + p;
        acc = acc * scale + p * zv;
        m = mn;
    }
    float o = (end > beg) ? acc / s : 0.f;
    o += act ? bias[lane] : 0.f;
    // log_softmax over the 40 classes (lanes >= 40 padded with -inf / 0)
    float v = act ? o : -3.0e38f;
    float mx = v;
    #pragma unroll
    for (int off = 32; off > 0; off >>= 1) mx = fmaxf(mx, __shfl_xor(mx, off));
    float p = act ? __expf(o - mx) : 0.f;
    float sum = p;
    #pragma unroll
    for (int off = 32; off > 0; off >>= 1) sum += __shfl_xor(sum, off);
    if (act) out[(size_t)n * 40 + lane] = o - mx - __logf(sum);
}

// ---------------------------------------------------------------------------
extern "C" void kernel_launch(void* const* d_in, const int* in_sizes, int n_in,
                              void* d_out, int out_size, void* d_ws, size_t ws_size,
                              hipStream_t stream) {
    const float* features = (const float*)d_in[0];
    const int*   src      = (const int*)d_in[1];
    const int*   dst      = (const int*)d_in[2];
    const float* W1  = (const float*)d_in[3];
    const float* al1 = (const float*)d_in[4];
    const float* ar1 = (const float*)d_in[5];
    const float* b1  = (const float*)d_in[6];
    const float* W2  = (const float*)d_in[7];
    const float* al2 = (const float*)d_in[8];
    const float* ar2 = (const float*)d_in[9];
    const float* b2  = (const float*)d_in[10];
    const float* W3  = (const float*)d_in[11];
    const float* al3 = (const float*)d_in[12];
    const float* ar3 = (const float*)d_in[13];
    const float* b3  = (const float*)d_in[14];
    float* out = (float*)d_out;

    const int N = NNODES, E = NEDGES;

    // workspace layout
    float* zbuf = (float*)d_ws;                       // N*128
    float* hbuf = zbuf + (size_t)N * 128;             // N*128
    float* elb  = hbuf + (size_t)N * 128;             // N*4
    float* erb  = elb + (size_t)N * 4;                // N*4
    int* row_ptr = (int*)(erb + (size_t)N * 4);       // N+1
    int* cursor  = row_ptr + ((N + 8) & ~7);          // N (also used as counts)
    int* csr_src = cursor + N;                        // E

    // ---- CSR build ----
    k_zero_int<<<(N + 255) / 256, 256, 0, stream>>>(cursor, N);
    k_hist<<<(E + 255) / 256, 256, 0, stream>>>(dst, cursor, E);
    k_scan<<<1, 1024, 0, stream>>>(cursor, row_ptr, N);
    k_copy_int<<<(N + 255) / 256, 256, 0, stream>>>(row_ptr, cursor, N);
    k_scatter<<<(E + 255) / 256, 256, 0, stream>>>(src, dst, cursor, csr_src, E);

    // ---- layer 1 ----
    gemm_n128<<<(N + 31) / 32, 256, 0, stream>>>(features, W1, zbuf, N, FIN);
    attn_scores128<<<N, 128, 0, stream>>>(zbuf, al1, ar1, elb, erb, N);
    gat_agg128<<<N, 128, 0, stream>>>(zbuf, elb, erb, row_ptr, csr_src, b1, hbuf, N);

    // ---- layer 2 ----
    gemm_n128<<<(N + 31) / 32, 256, 0, stream>>>(hbuf, W2, zbuf, N, HIDDEN);
    attn_scores128<<<N, 128, 0, stream>>>(zbuf, al2, ar2, elb, erb, N);
    gat_agg128<<<N, 128, 0, stream>>>(zbuf, elb, erb, row_ptr, csr_src, b2, hbuf, N);

    // ---- layer 3 ----
    gemm_n40<<<(N + 3) / 4, 256, 0, stream>>>(hbuf, W3, zbuf, N);
    attn_scores40<<<(N + 3) / 4, 256, 0, stream>>>(zbuf, al3, ar3, elb, erb, N);
    gat_agg40_lsm<<<(N + 3) / 4, 256, 0, stream>>>(zbuf, elb, erb, row_ptr, csr_src, b3, out, N);

    (void)in_sizes; (void)n_in; (void)out_size; (void)ws_size;
}

// Round 2
// 527.867 us; speedup vs baseline: 1.1886x; 1.1886x over previous
//
#include <hip/hip_runtime.h>
#include <hip/hip_bf16.h>
#include <math.h>

// Problem constants (GAT_66907000537778)
#define NNODES 50000
#define NEDGES 800000
#define FIN 256
#define HID 32
#define HEADS 4
#define OUTS 40
#define HIDDEN 128   // HEADS*HID

typedef __bf16 bf16x8 __attribute__((ext_vector_type(8)));
typedef float  f32x4  __attribute__((ext_vector_type(4)));

// ---------------------------------------------------------------------------
// CSR construction (grouped by dst)
// ---------------------------------------------------------------------------
__global__ void k_zero_int(int* __restrict__ p, int n) {
    int i = blockIdx.x * blockDim.x + threadIdx.x;
    if (i < n) p[i] = 0;
}

__global__ void k_hist(const int* __restrict__ dst, int* __restrict__ counts, int n) {
    int i = blockIdx.x * blockDim.x + threadIdx.x;
    if (i < n) atomicAdd(&counts[dst[i]], 1);
}

__global__ __launch_bounds__(1024) void k_scan(const int* __restrict__ counts,
                                               int* __restrict__ row_ptr, int n) {
    __shared__ int wsum[16];
    __shared__ int carry_s;
    int tid = threadIdx.x;
    int lane = tid & 63, wid = tid >> 6;
    if (tid == 0) carry_s = 0;
    __syncthreads();
    for (int base = 0; base < n; base += 1024) {
        int i = base + tid;
        int v = (i < n) ? counts[i] : 0;
        int x = v;
        #pragma unroll
        for (int off = 1; off < 64; off <<= 1) {
            int t = __shfl_up(x, off);
            if (lane >= off) x += t;
        }
        if (lane == 63) wsum[wid] = x;
        __syncthreads();
        int carry = carry_s;
        int woff = 0;
        for (int w = 0; w < wid; ++w) woff += wsum[w];
        int incl = x + woff;
        if (i < n) row_ptr[i] = carry + incl - v;   // exclusive
        __syncthreads();
        if (tid == 1023) carry_s = carry + incl;
        __syncthreads();
    }
    if (tid == 0) row_ptr[n] = carry_s;
}

__global__ void k_copy_int(const int* __restrict__ a, int* __restrict__ b, int n) {
    int i = blockIdx.x * blockDim.x + threadIdx.x;
    if (i < n) b[i] = a[i];
}

__global__ void k_scatter(const int* __restrict__ src, const int* __restrict__ dst,
                          int* __restrict__ cursor, int* __restrict__ csr_src, int n) {
    int i = blockIdx.x * blockDim.x + threadIdx.x;
    if (i < n) {
        int p = atomicAdd(&cursor[dst[i]], 1);
        csr_src[p] = src[i];
    }
}

// ---------------------------------------------------------------------------
// dtype converts
// ---------------------------------------------------------------------------
__global__ void k_f2b(const float* __restrict__ in, __bf16* __restrict__ out, int n8) {
    int i = blockIdx.x * blockDim.x + threadIdx.x;
    if (i >= n8) return;
    const float4* p = reinterpret_cast<const float4*>(in) + (size_t)i * 2;
    float4 a = p[0], b = p[1];
    __bf16 t[8] = {(__bf16)a.x, (__bf16)a.y, (__bf16)a.z, (__bf16)a.w,
                   (__bf16)b.x, (__bf16)b.y, (__bf16)b.z, (__bf16)b.w};
    *reinterpret_cast<uint4*>(&out[(size_t)i * 8]) = *reinterpret_cast<uint4*>(t);
}

// W [K][128] f32 -> Wt [128][K] bf16
__global__ void k_wt(const float* __restrict__ W, __bf16* __restrict__ Wt, int K) {
    int i = blockIdx.x * blockDim.x + threadIdx.x;
    if (i >= K * 128) return;
    int k = i >> 7, c = i & 127;
    Wt[(size_t)c * K + k] = (__bf16)W[i];
}

// ---------------------------------------------------------------------------
// MFMA bf16 GEMM, N=128, fused attention-score epilogue.
// Block 256 thr = 4 waves; tile 64(M) x 128(N); K-step 32.
// Outputs: z bf16 [M][128], el/er f32 [M][4].
// ---------------------------------------------------------------------------
__global__ __launch_bounds__(256) void gemm_mfma_128(
    const __bf16* __restrict__ A, const __bf16* __restrict__ Wt,
    const float* __restrict__ al, const float* __restrict__ ar,
    __bf16* __restrict__ z, float* __restrict__ el, float* __restrict__ er,
    int M, int K)
{
    // rows padded to 40 bf16 (80 B) -> 16B-aligned, banks spread (2-way max)
    __shared__ alignas(16) __bf16 As[64 * 40];
    __shared__ alignas(16) __bf16 Bs[128 * 40];
    int tid = threadIdx.x;
    int wv = tid >> 6, l = tid & 63;
    int lr = l & 15, lk = l >> 4;
    int m0 = blockIdx.x * 64;
    f32x4 acc[8];
    f32x4 zero4 = {0.f, 0.f, 0.f, 0.f};
    #pragma unroll
    for (int nt = 0; nt < 8; ++nt) acc[nt] = zero4;

    int ar_ = tid >> 2, aq = tid & 3;   // A staging: row, 16B chunk
    for (int k0 = 0; k0 < K; k0 += 32) {
        {   // A tile: 64 x 32 bf16
            int m = m0 + ar_;
            uint4 av = make_uint4(0, 0, 0, 0);
            if (m < M) av = *reinterpret_cast<const uint4*>(&A[(size_t)m * K + k0 + aq * 8]);
            *reinterpret_cast<uint4*>(&As[ar_ * 40 + aq * 8]) = av;
        }
        {   // B tile: Wt rows (col-major W): 128 x 32 bf16
            #pragma unroll
            for (int t = 0; t < 2; ++t) {
                int cid = tid + t * 256;
                int c = cid >> 2, q = cid & 3;
                *reinterpret_cast<uint4*>(&Bs[c * 40 + q * 8]) =
                    *reinterpret_cast<const uint4*>(&Wt[(size_t)c * K + k0 + q * 8]);
            }
        }
        __syncthreads();
        bf16x8 af = *reinterpret_cast<const bf16x8*>(&As[(wv * 16 + lr) * 40 + lk * 8]);
        #pragma unroll
        for (int nt = 0; nt < 8; ++nt) {
            bf16x8 bfr = *reinterpret_cast<const bf16x8*>(&Bs[(nt * 16 + lr) * 40 + lk * 8]);
            acc[nt] = __builtin_amdgcn_mfma_f32_16x16x32_bf16(af, bfr, acc[nt], 0, 0, 0);
        }
        __syncthreads();
    }

    // epilogue: z store (bf16) + fused el/er row-dots
    float alv[8], arv[8];
    #pragma unroll
    for (int nt = 0; nt < 8; ++nt) {
        alv[nt] = al[nt * 16 + lr];
        arv[nt] = ar[nt * 16 + lr];
    }
    #pragma unroll
    for (int r = 0; r < 4; ++r) {
        int m = m0 + wv * 16 + lk * 4 + r;   // C/D: row=(lane>>4)*4+reg, col=lane&15
        float pel[4], per_[4];
        #pragma unroll
        for (int h = 0; h < 4; ++h) {
            pel[h]  = acc[2 * h][r] * alv[2 * h] + acc[2 * h + 1][r] * alv[2 * h + 1];
            per_[h] = acc[2 * h][r] * arv[2 * h] + acc[2 * h + 1][r] * arv[2 * h + 1];
        }
        #pragma unroll
        for (int mk = 1; mk < 16; mk <<= 1) {
            #pragma unroll
            for (int h = 0; h < 4; ++h) {
                pel[h]  += __shfl_xor(pel[h], mk);
                per_[h] += __shfl_xor(per_[h], mk);
            }
        }
        if (m < M) {
            #pragma unroll
            for (int nt = 0; nt < 8; ++nt)
                z[(size_t)m * 128 + nt * 16 + lr] = (__bf16)acc[nt][r];
            if (lr == 0) {
                #pragma unroll
                for (int h = 0; h < 4; ++h) {
                    el[m * 4 + h] = pel[h];
                    er[m * 4 + h] = per_[h];
                }
            }
        }
    }
}

// ---------------------------------------------------------------------------
// fused edge-softmax + aggregation, layers 1-2 (H=4, F=32), bf16 gather
// ---------------------------------------------------------------------------
__global__ __launch_bounds__(128) void gat_agg128p(
    const __bf16* __restrict__ z, const float* __restrict__ el,
    const float* __restrict__ er, const int* __restrict__ rp,
    const int* __restrict__ cs, const float* __restrict__ bias,
    __bf16* __restrict__ hout, int n_nodes)
{
    int nd = blockIdx.x;
    if (nd >= n_nodes) return;
    int h = threadIdx.x >> 5, f = threadIdx.x & 31;
    int beg = rp[nd], end = rp[nd + 1];
    float erv = er[nd * 4 + h];
    float m = -3.0e38f, s = 0.f, acc = 0.f;
    int sidx = (beg < end) ? cs[beg] : 0;
    for (int j = beg; j < end; ++j) {
        int nsx = (j + 1 < end) ? cs[j + 1] : 0;
        float e = el[sidx * 4 + h] + erv;
        e = (e > 0.f) ? e : 0.2f * e;
        float zv = (float)z[(size_t)sidx * 128 + h * 32 + f];
        float mn = fmaxf(m, e);
        float scl = __expf(m - mn);
        float p = __expf(e - mn);
        s = s * scl + p;
        acc = acc * scl + p * zv;
        m = mn;
        sidx = nsx;
    }
    float o = (end > beg) ? acc / s : 0.f;
    o += bias[h * 32 + f];
    o = fmaxf(o, 0.f);   // relu (layers 1-2)
    hout[(size_t)nd * 128 + h * 32 + f] = (__bf16)o;
}

// ---------------------------------------------------------------------------
// layer-3 GEMM (N=40) from bf16 input + fused el/er; z40 rows padded to 64
// ---------------------------------------------------------------------------
__global__ __launch_bounds__(256) void gemm40_attn(
    const __bf16* __restrict__ A, const float* __restrict__ W,
    const float* __restrict__ al, const float* __restrict__ arr,
    __bf16* __restrict__ z40, float* __restrict__ el3, float* __restrict__ er3,
    int M)
{
    __shared__ float Wl[128 * 40];
    __shared__ float rows[4][128];
    int tid = threadIdx.x, wid = tid >> 6, lane = tid & 63;
    int m = blockIdx.x * 4 + wid;
    for (int j = tid; j < 128 * 40; j += 256) Wl[j] = W[j];
    if (m < M && lane < 32) {
        const __bf16* ap = &A[(size_t)m * 128 + lane * 4];
        #pragma unroll
        for (int i = 0; i < 4; ++i) rows[wid][lane * 4 + i] = (float)ap[i];
    }
    __syncthreads();
    if (m >= M) return;
    bool act = lane < 40;
    float o = 0.f;
    if (act) {
        #pragma unroll 8
        for (int k = 0; k < 128; ++k) o += rows[wid][k] * Wl[k * 40 + lane];
    }
    float a = act ? o * al[lane] : 0.f;
    float b = act ? o * arr[lane] : 0.f;
    #pragma unroll
    for (int off = 32; off > 0; off >>= 1) {
        a += __shfl_xor(a, off);
        b += __shfl_xor(b, off);
    }
    if (act) z40[(size_t)m * 64 + lane] = (__bf16)o;
    if (lane == 0) { el3[m] = a; er3[m] = b; }
}

// ---------------------------------------------------------------------------
// layer 3 aggregation: H=1, F=40, + bias + log_softmax -> final output
// ---------------------------------------------------------------------------
__global__ __launch_bounds__(256) void gat_agg40_lsm(
    const __bf16* __restrict__ z40, const float* __restrict__ el3,
    const float* __restrict__ er3, const int* __restrict__ rp,
    const int* __restrict__ cs, const float* __restrict__ bias,
    float* __restrict__ out, int n_nodes)
{
    int tid = threadIdx.x, wid = tid >> 6, lane = tid & 63;
    int nd = blockIdx.x * 4 + wid;
    if (nd >= n_nodes) return;
    bool act = lane < 40;
    int beg = rp[nd], end = rp[nd + 1];
    float erv = er3[nd];
    float m = -3.0e38f, s = 0.f, acc = 0.f;
    int sidx = (beg < end) ? cs[beg] : 0;
    for (int j = beg; j < end; ++j) {
        int nsx = (j + 1 < end) ? cs[j + 1] : 0;
        float e = el3[sidx] + erv;
        e = (e > 0.f) ? e : 0.2f * e;
        float zv = act ? (float)z40[(size_t)sidx * 64 + lane] : 0.f;
        float mn = fmaxf(m, e);
        float scl = __expf(m - mn);
        float p = __expf(e - mn);
        s = s * scl + p;
        acc = acc * scl + p * zv;
        m = mn;
        sidx = nsx;
    }
    float o = (end > beg) ? acc / s : 0.f;
    o += act ? bias[lane] : 0.f;
    float v = act ? o : -3.0e38f;
    float mx = v;
    #pragma unroll
    for (int off = 32; off > 0; off >>= 1) mx = fmaxf(mx, __shfl_xor(mx, off));
    float p2 = act ? __expf(o - mx) : 0.f;
    float sum = p2;
    #pragma unroll
    for (int off = 32; off > 0; off >>= 1) sum += __shfl_xor(sum, off);
    if (act) out[(size_t)nd * 40 + lane] = o - mx - __logf(sum);
}

// ---------------------------------------------------------------------------
extern "C" void kernel_launch(void* const* d_in, const int* in_sizes, int n_in,
                              void* d_out, int out_size, void* d_ws, size_t ws_size,
                              hipStream_t stream) {
    const float* features = (const float*)d_in[0];
    const int*   src      = (const int*)d_in[1];
    const int*   dst      = (const int*)d_in[2];
    const float* W1  = (const float*)d_in[3];
    const float* al1 = (const float*)d_in[4];
    const float* ar1 = (const float*)d_in[5];
    const float* b1  = (const float*)d_in[6];
    const float* W2  = (const float*)d_in[7];
    const float* al2 = (const float*)d_in[8];
    const float* ar2 = (const float*)d_in[9];
    const float* b2  = (const float*)d_in[10];
    const float* W3  = (const float*)d_in[11];
    const float* al3 = (const float*)d_in[12];
    const float* ar3 = (const float*)d_in[13];
    const float* b3  = (const float*)d_in[14];
    float* out = (float*)d_out;

    const int N = NNODES, E = NEDGES;

    // workspace layout (bytes)
    char* ws = (char*)d_ws;
    __bf16* feat_b = (__bf16*)(ws + 0);            // N*256*2 = 25,600,000
    __bf16* z40    = feat_b;                       // alias (layer 3; feat dead)
    __bf16* zb     = (__bf16*)(ws + 25600000);     // N*128*2 = 12,800,000
    __bf16* hb     = (__bf16*)(ws + 38400000);     // N*128*2 = 12,800,000
    float*  elb    = (float*)(ws + 51200000);      // N*4*4   =    800,000
    float*  erb    = (float*)(ws + 52000000);      // N*4*4   =    800,000
    __bf16* Wt1    = (__bf16*)(ws + 52800000);     // 128*256*2 =   65,536
    __bf16* Wt2    = (__bf16*)(ws + 52865536);     // 128*128*2 =   32,768
    int* row_ptr   = (int*)(ws + 52898304);        // (N+1)*4
    int* cursor    = (int*)(ws + 53098496);        // N*4
    int* csr_src   = (int*)(ws + 53298496);        // E*4 -> ends 56,498,496

    // ---- CSR build ----
    k_zero_int<<<(N + 255) / 256, 256, 0, stream>>>(cursor, N);
    k_hist<<<(E + 255) / 256, 256, 0, stream>>>(dst, cursor, E);
    k_scan<<<1, 1024, 0, stream>>>(cursor, row_ptr, N);
    k_copy_int<<<(N + 255) / 256, 256, 0, stream>>>(row_ptr, cursor, N);
    k_scatter<<<(E + 255) / 256, 256, 0, stream>>>(src, dst, cursor, csr_src, E);

    // ---- precision converts ----
    k_f2b<<<(N * 256 / 8 + 255) / 256, 256, 0, stream>>>(features, feat_b, N * 256 / 8);
    k_wt<<<(256 * 128 + 255) / 256, 256, 0, stream>>>(W1, Wt1, 256);
    k_wt<<<(128 * 128 + 255) / 256, 256, 0, stream>>>(W2, Wt2, 128);

    // ---- layer 1 ----
    gemm_mfma_128<<<(N + 63) / 64, 256, 0, stream>>>(feat_b, Wt1, al1, ar1, zb, elb, erb, N, 256);
    gat_agg128p<<<N, 128, 0, stream>>>(zb, elb, erb, row_ptr, csr_src, b1, hb, N);

    // ---- layer 2 ----
    gemm_mfma_128<<<(N + 63) / 64, 256, 0, stream>>>(hb, Wt2, al2, ar2, zb, elb, erb, N, 128);
    gat_agg128p<<<N, 128, 0, stream>>>(zb, elb, erb, row_ptr, csr_src, b2, hb, N);

    // ---- layer 3 ----
    gemm40_attn<<<(N + 3) / 4, 256, 0, stream>>>(hb, W3, al3, ar3, z40, elb, erb, N);
    gat_agg40_lsm<<<(N + 3) / 4, 256, 0, stream>>>(z40, elb, erb, row_ptr, csr_src, b3, out, N);

    (void)in_sizes; (void)n_in; (void)out_size; (void)ws_size;
}

// Round 3
// 362.451 us; speedup vs baseline: 1.7310x; 1.4564x over previous
//
#include <hip/hip_runtime.h>
#include <hip/hip_bf16.h>
#include <math.h>

// Problem constants (GAT_66907000537778)
#define NNODES 50000
#define NEDGES 800000
#define FIN 256
#define HID 32
#define HEADS 4
#define OUTS 40
#define HIDDEN 128   // HEADS*HID

typedef __bf16 bf16x8 __attribute__((ext_vector_type(8)));
typedef float  f32x4  __attribute__((ext_vector_type(4)));

// ---------------------------------------------------------------------------
// CSR construction (grouped by dst)
// ---------------------------------------------------------------------------
__global__ void k_zero_int(int* __restrict__ p, int n) {
    int i = blockIdx.x * blockDim.x + threadIdx.x;
    if (i < n) p[i] = 0;
}

__global__ void k_hist(const int* __restrict__ dst, int* __restrict__ counts, int n) {
    int i = blockIdx.x * blockDim.x + threadIdx.x;
    if (i < n) atomicAdd(&counts[dst[i]], 1);
}

__global__ __launch_bounds__(1024) void k_scan(const int* __restrict__ counts,
                                               int* __restrict__ row_ptr, int n) {
    __shared__ int wsum[16];
    __shared__ int carry_s;
    int tid = threadIdx.x;
    int lane = tid & 63, wid = tid >> 6;
    if (tid == 0) carry_s = 0;
    __syncthreads();
    for (int base = 0; base < n; base += 1024) {
        int i = base + tid;
        int v = (i < n) ? counts[i] : 0;
        int x = v;
        #pragma unroll
        for (int off = 1; off < 64; off <<= 1) {
            int t = __shfl_up(x, off);
            if (lane >= off) x += t;
        }
        if (lane == 63) wsum[wid] = x;
        __syncthreads();
        int carry = carry_s;
        int woff = 0;
        for (int w = 0; w < wid; ++w) woff += wsum[w];
        int incl = x + woff;
        if (i < n) row_ptr[i] = carry + incl - v;   // exclusive
        __syncthreads();
        if (tid == 1023) carry_s = carry + incl;
        __syncthreads();
    }
    if (tid == 0) row_ptr[n] = carry_s;
}

__global__ void k_copy_int(const int* __restrict__ a, int* __restrict__ b, int n) {
    int i = blockIdx.x * blockDim.x + threadIdx.x;
    if (i < n) b[i] = a[i];
}

__global__ void k_scatter(const int* __restrict__ src, const int* __restrict__ dst,
                          int* __restrict__ cursor, int* __restrict__ csr_src, int n) {
    int i = blockIdx.x * blockDim.x + threadIdx.x;
    if (i < n) {
        int p = atomicAdd(&cursor[dst[i]], 1);
        csr_src[p] = src[i];
    }
}

// ---------------------------------------------------------------------------
// dtype converts
// ---------------------------------------------------------------------------
__global__ void k_f2b(const float* __restrict__ in, __bf16* __restrict__ out, int n8) {
    int i = blockIdx.x * blockDim.x + threadIdx.x;
    if (i >= n8) return;
    const float4* p = reinterpret_cast<const float4*>(in) + (size_t)i * 2;
    float4 a = p[0], b = p[1];
    __bf16 t[8] = {(__bf16)a.x, (__bf16)a.y, (__bf16)a.z, (__bf16)a.w,
                   (__bf16)b.x, (__bf16)b.y, (__bf16)b.z, (__bf16)b.w};
    *reinterpret_cast<uint4*>(&out[(size_t)i * 8]) = *reinterpret_cast<uint4*>(t);
}

// W [K][128] f32 -> Wt [128][K] bf16
__global__ void k_wt(const float* __restrict__ W, __bf16* __restrict__ Wt, int K) {
    int i = blockIdx.x * blockDim.x + threadIdx.x;
    if (i >= K * 128) return;
    int k = i >> 7, c = i & 127;
    Wt[(size_t)c * K + k] = (__bf16)W[i];
}

// ---------------------------------------------------------------------------
// MFMA bf16 GEMM, N=128, fused attention-score epilogue.
// ---------------------------------------------------------------------------
__global__ __launch_bounds__(256) void gemm_mfma_128(
    const __bf16* __restrict__ A, const __bf16* __restrict__ Wt,
    const float* __restrict__ al, const float* __restrict__ ar,
    __bf16* __restrict__ z, float* __restrict__ el, float* __restrict__ er,
    int M, int K)
{
    __shared__ alignas(16) __bf16 As[64 * 40];
    __shared__ alignas(16) __bf16 Bs[128 * 40];
    int tid = threadIdx.x;
    int wv = tid >> 6, l = tid & 63;
    int lr = l & 15, lk = l >> 4;
    int m0 = blockIdx.x * 64;
    f32x4 acc[8];
    f32x4 zero4 = {0.f, 0.f, 0.f, 0.f};
    #pragma unroll
    for (int nt = 0; nt < 8; ++nt) acc[nt] = zero4;

    int ar_ = tid >> 2, aq = tid & 3;
    for (int k0 = 0; k0 < K; k0 += 32) {
        {
            int m = m0 + ar_;
            uint4 av = make_uint4(0, 0, 0, 0);
            if (m < M) av = *reinterpret_cast<const uint4*>(&A[(size_t)m * K + k0 + aq * 8]);
            *reinterpret_cast<uint4*>(&As[ar_ * 40 + aq * 8]) = av;
        }
        {
            #pragma unroll
            for (int t = 0; t < 2; ++t) {
                int cid = tid + t * 256;
                int c = cid >> 2, q = cid & 3;
                *reinterpret_cast<uint4*>(&Bs[c * 40 + q * 8]) =
                    *reinterpret_cast<const uint4*>(&Wt[(size_t)c * K + k0 + q * 8]);
            }
        }
        __syncthreads();
        bf16x8 af = *reinterpret_cast<const bf16x8*>(&As[(wv * 16 + lr) * 40 + lk * 8]);
        #pragma unroll
        for (int nt = 0; nt < 8; ++nt) {
            bf16x8 bfr = *reinterpret_cast<const bf16x8*>(&Bs[(nt * 16 + lr) * 40 + lk * 8]);
            acc[nt] = __builtin_amdgcn_mfma_f32_16x16x32_bf16(af, bfr, acc[nt], 0, 0, 0);
        }
        __syncthreads();
    }

    float alv[8], arv[8];
    #pragma unroll
    for (int nt = 0; nt < 8; ++nt) {
        alv[nt] = al[nt * 16 + lr];
        arv[nt] = ar[nt * 16 + lr];
    }
    #pragma unroll
    for (int r = 0; r < 4; ++r) {
        int m = m0 + wv * 16 + lk * 4 + r;   // C/D: row=(lane>>4)*4+reg, col=lane&15
        float pel[4], per_[4];
        #pragma unroll
        for (int h = 0; h < 4; ++h) {
            pel[h]  = acc[2 * h][r] * alv[2 * h] + acc[2 * h + 1][r] * alv[2 * h + 1];
            per_[h] = acc[2 * h][r] * arv[2 * h] + acc[2 * h + 1][r] * arv[2 * h + 1];
        }
        #pragma unroll
        for (int mk = 1; mk < 16; mk <<= 1) {
            #pragma unroll
            for (int h = 0; h < 4; ++h) {
                pel[h]  += __shfl_xor(pel[h], mk);
                per_[h] += __shfl_xor(per_[h], mk);
            }
        }
        if (m < M) {
            #pragma unroll
            for (int nt = 0; nt < 8; ++nt)
                z[(size_t)m * 128 + nt * 16 + lr] = (__bf16)acc[nt][r];
            if (lr == 0) {
                #pragma unroll
                for (int h = 0; h < 4; ++h) {
                    el[m * 4 + h] = pel[h];
                    er[m * 4 + h] = per_[h];
                }
            }
        }
    }
}

// ---------------------------------------------------------------------------
// chunk-parallel edge-softmax + aggregation, layers 1-2 (H=4, F=32)
// block 128 = 2 waves, 4 head-groups of 32 lanes; 1 node per block.
// phase 1: lane<->edge parallel score+exp; phase 2: unroll-8 gather fma.
// ---------------------------------------------------------------------------
__global__ __launch_bounds__(128) void gat_agg128c(
    const __bf16* __restrict__ z, const float* __restrict__ el,
    const float* __restrict__ er, const int* __restrict__ rp,
    const int* __restrict__ cs, const float* __restrict__ bias,
    __bf16* __restrict__ hout, int n_nodes)
{
    __shared__ uint2 sh[4][32];   // per head-group: {z element offset, p bits}
    int nd = blockIdx.x;
    if (nd >= n_nodes) return;
    int t = threadIdx.x;
    int h = t >> 5, f = t & 31;
    int beg = rp[nd], end = rp[nd + 1];
    float erv = er[nd * 4 + h];
    float m = -3.0e38f, s = 0.f, acc = 0.f;
    const int zoff = h * 32 + f;

    for (int c0 = beg; c0 < end; c0 += 32) {
        int ch = end - c0; if (ch > 32) ch = 32;
        int chp = (ch + 7) & ~7;
        // ---- phase 1: per-lane edge scores ----
        int sidx = (f < ch) ? cs[c0 + f] : 0;
        float e = -3.0e38f;
        if (f < ch) {
            float ev = el[sidx * 4 + h] + erv;
            e = (ev > 0.f) ? ev : 0.2f * ev;
        }
        float cm = e;
        #pragma unroll
        for (int mk = 16; mk; mk >>= 1) cm = fmaxf(cm, __shfl_xor(cm, mk));
        float nm = fmaxf(m, cm);
        float p = (f < ch) ? __expf(e - nm) : 0.f;
        float ps = p;
        #pragma unroll
        for (int mk = 16; mk; mk >>= 1) ps += __shfl_xor(ps, mk);
        float so = __expf(m - nm);
        s = s * so + ps;
        acc *= so;
        m = nm;
        sh[h][f] = make_uint2((unsigned)(sidx << 7), __float_as_uint(p));
        // wave-local LDS (each 32-group reads only what it wrote); no barrier
        // ---- phase 2: unroll-8 gather + fma ----
        for (int k = 0; k < chp; k += 8) {
            float zv[8], pk[8];
            #pragma unroll
            for (int u = 0; u < 8; ++u) {
                uint2 v = sh[h][k + u];
                pk[u] = __uint_as_float(v.y);
                zv[u] = (float)z[(size_t)v.x + zoff];
            }
            #pragma unroll
            for (int u = 0; u < 8; ++u) acc += pk[u] * zv[u];
        }
    }
    float o = (end > beg) ? acc / s : 0.f;
    o += bias[zoff];
    o = fmaxf(o, 0.f);   // relu (layers 1-2)
    hout[(size_t)nd * 128 + zoff] = (__bf16)o;
}

// ---------------------------------------------------------------------------
// layer-3 GEMM (N=40) from bf16 input + fused el/er; z40 rows padded to 64
// ---------------------------------------------------------------------------
__global__ __launch_bounds__(256) void gemm40_attn(
    const __bf16* __restrict__ A, const float* __restrict__ W,
    const float* __restrict__ al, const float* __restrict__ arr,
    __bf16* __restrict__ z40, float* __restrict__ el3, float* __restrict__ er3,
    int M)
{
    __shared__ float Wl[128 * 40];
    __shared__ float rows[4][128];
    int tid = threadIdx.x, wid = tid >> 6, lane = tid & 63;
    int m = blockIdx.x * 4 + wid;
    for (int j = tid; j < 128 * 40; j += 256) Wl[j] = W[j];
    if (m < M && lane < 32) {
        const __bf16* ap = &A[(size_t)m * 128 + lane * 4];
        #pragma unroll
        for (int i = 0; i < 4; ++i) rows[wid][lane * 4 + i] = (float)ap[i];
    }
    __syncthreads();
    if (m >= M) return;
    bool act = lane < 40;
    float o = 0.f;
    if (act) {
        #pragma unroll 8
        for (int k = 0; k < 128; ++k) o += rows[wid][k] * Wl[k * 40 + lane];
    }
    float a = act ? o * al[lane] : 0.f;
    float b = act ? o * arr[lane] : 0.f;
    #pragma unroll
    for (int off = 32; off > 0; off >>= 1) {
        a += __shfl_xor(a, off);
        b += __shfl_xor(b, off);
    }
    if (act) z40[(size_t)m * 64 + lane] = (__bf16)o;
    if (lane == 0) { el3[m] = a; er3[m] = b; }
}

// ---------------------------------------------------------------------------
// layer-3 aggregation: chunk-parallel, 1 node per wave, + bias + log_softmax
// ---------------------------------------------------------------------------
__global__ __launch_bounds__(256) void gat_agg40c(
    const __bf16* __restrict__ z40, const float* __restrict__ el3,
    const float* __restrict__ er3, const int* __restrict__ rp,
    const int* __restrict__ cs, const float* __restrict__ bias,
    float* __restrict__ out, int n_nodes)
{
    __shared__ uint2 sh[4][64];
    int tid = threadIdx.x, wid = tid >> 6, lane = tid & 63;
    int nd = blockIdx.x * 4 + wid;
    if (nd >= n_nodes) return;
    bool act = lane < 40;
    int beg = rp[nd], end = rp[nd + 1];
    float erv = er3[nd];
    float m = -3.0e38f, s = 0.f, acc = 0.f;

    for (int c0 = beg; c0 < end; c0 += 64) {
        int ch = end - c0; if (ch > 64) ch = 64;
        int chp = (ch + 7) & ~7;
        int sidx = (lane < ch) ? cs[c0 + lane] : 0;
        float e = -3.0e38f;
        if (lane < ch) {
            float ev = el3[sidx] + erv;
            e = (ev > 0.f) ? ev : 0.2f * ev;
        }
        float cm = e;
        #pragma unroll
        for (int mk = 32; mk; mk >>= 1) cm = fmaxf(cm, __shfl_xor(cm, mk));
        float nm = fmaxf(m, cm);
        float p = (lane < ch) ? __expf(e - nm) : 0.f;
        float ps = p;
        #pragma unroll
        for (int mk = 32; mk; mk >>= 1) ps += __shfl_xor(ps, mk);
        float so = __expf(m - nm);
        s = s * so + ps;
        acc *= so;
        m = nm;
        sh[wid][lane] = make_uint2((unsigned)(sidx << 6), __float_as_uint(p));
        for (int k = 0; k < chp; k += 8) {
            float zv[8], pk[8];
            #pragma unroll
            for (int u = 0; u < 8; ++u) {
                uint2 v = sh[wid][k + u];
                pk[u] = __uint_as_float(v.y);
                zv[u] = (float)z40[(size_t)v.x + lane];   // lanes>=40 read pad, discarded
            }
            #pragma unroll
            for (int u = 0; u < 8; ++u) acc += pk[u] * zv[u];
        }
    }
    float o = (end > beg) ? acc / s : 0.f;
    o += act ? bias[lane] : 0.f;
    float v = act ? o : -3.0e38f;
    float mx = v;
    #pragma unroll
    for (int off = 32; off > 0; off >>= 1) mx = fmaxf(mx, __shfl_xor(mx, off));
    float p2 = act ? __expf(o - mx) : 0.f;
    float sum = p2;
    #pragma unroll
    for (int off = 32; off > 0; off >>= 1) sum += __shfl_xor(sum, off);
    if (act) out[(size_t)nd * 40 + lane] = o - mx - __logf(sum);
}

// ---------------------------------------------------------------------------
extern "C" void kernel_launch(void* const* d_in, const int* in_sizes, int n_in,
                              void* d_out, int out_size, void* d_ws, size_t ws_size,
                              hipStream_t stream) {
    const float* features = (const float*)d_in[0];
    const int*   src      = (const int*)d_in[1];
    const int*   dst      = (const int*)d_in[2];
    const float* W1  = (const float*)d_in[3];
    const float* al1 = (const float*)d_in[4];
    const float* ar1 = (const float*)d_in[5];
    const float* b1  = (const float*)d_in[6];
    const float* W2  = (const float*)d_in[7];
    const float* al2 = (const float*)d_in[8];
    const float* ar2 = (const float*)d_in[9];
    const float* b2  = (const float*)d_in[10];
    const float* W3  = (const float*)d_in[11];
    const float* al3 = (const float*)d_in[12];
    const float* ar3 = (const float*)d_in[13];
    const float* b3  = (const float*)d_in[14];
    float* out = (float*)d_out;

    const int N = NNODES, E = NEDGES;

    // workspace layout (bytes)
    char* ws = (char*)d_ws;
    __bf16* feat_b = (__bf16*)(ws + 0);            // N*256*2 = 25,600,000
    __bf16* z40    = feat_b;                       // alias (layer 3; feat dead), stride 64
    __bf16* zb     = (__bf16*)(ws + 25600000);     // N*128*2
    __bf16* hb     = (__bf16*)(ws + 38400000);     // N*128*2
    float*  elb    = (float*)(ws + 51200000);      // N*4*4
    float*  erb    = (float*)(ws + 52000000);      // N*4*4
    __bf16* Wt1    = (__bf16*)(ws + 52800000);     // 128*256*2
    __bf16* Wt2    = (__bf16*)(ws + 52865536);     // 128*128*2
    int* row_ptr   = (int*)(ws + 52898304);        // (N+1)*4
    int* cursor    = (int*)(ws + 53098496);        // N*4
    int* csr_src   = (int*)(ws + 53298496);        // E*4 -> ends 56,498,496

    // ---- CSR build ----
    k_zero_int<<<(N + 255) / 256, 256, 0, stream>>>(cursor, N);
    k_hist<<<(E + 255) / 256, 256, 0, stream>>>(dst, cursor, E);
    k_scan<<<1, 1024, 0, stream>>>(cursor, row_ptr, N);
    k_copy_int<<<(N + 255) / 256, 256, 0, stream>>>(row_ptr, cursor, N);
    k_scatter<<<(E + 255) / 256, 256, 0, stream>>>(src, dst, cursor, csr_src, E);

    // ---- precision converts ----
    k_f2b<<<(N * 256 / 8 + 255) / 256, 256, 0, stream>>>(features, feat_b, N * 256 / 8);
    k_wt<<<(256 * 128 + 255) / 256, 256, 0, stream>>>(W1, Wt1, 256);
    k_wt<<<(128 * 128 + 255) / 256, 256, 0, stream>>>(W2, Wt2, 128);

    // ---- layer 1 ----
    gemm_mfma_128<<<(N + 63) / 64, 256, 0, stream>>>(feat_b, Wt1, al1, ar1, zb, elb, erb, N, 256);
    gat_agg128c<<<N, 128, 0, stream>>>(zb, elb, erb, row_ptr, csr_src, b1, hb, N);

    // ---- layer 2 ----
    gemm_mfma_128<<<(N + 63) / 64, 256, 0, stream>>>(hb, Wt2, al2, ar2, zb, elb, erb, N, 128);
    gat_agg128c<<<N, 128, 0, stream>>>(zb, elb, erb, row_ptr, csr_src, b2, hb, N);

    // ---- layer 3 ----
    gemm40_attn<<<(N + 3) / 4, 256, 0, stream>>>(hb, W3, al3, ar3, z40, elb, erb, N);
    gat_agg40c<<<(N + 3) / 4, 256, 0, stream>>>(z40, elb, erb, row_ptr, csr_src, b3, out, N);

    (void)in_sizes; (void)n_in; (void)out_size; (void)ws_size;
}

// Round 4
// 291.071 us; speedup vs baseline: 2.1555x; 1.2452x over previous
//
#include <hip/hip_runtime.h>
#include <hip/hip_bf16.h>
#include <math.h>

// Problem constants (GAT_66907000537778)
#define NNODES 50000
#define NEDGES 800000
#define FIN 256
#define HID 32
#define HEADS 4
#define OUTS 40
#define HIDDEN 128   // HEADS*HID
#define NPART 8      // scatter partitions (dst ranges); 50000/8 = 6250

typedef __bf16 bf16x8 __attribute__((ext_vector_type(8)));
typedef float  f32x4  __attribute__((ext_vector_type(4)));

// ---------------------------------------------------------------------------
// CSR construction (grouped by dst)
// ---------------------------------------------------------------------------
__global__ void k_hist(const int* __restrict__ dst, int* __restrict__ counts, int n) {
    int i = blockIdx.x * blockDim.x + threadIdx.x;
    if (i < n) atomicAdd(&counts[dst[i]], 1);
}

// scan stage 1: per-block (256 elems) exclusive scan; block totals to bsum
__global__ __launch_bounds__(256) void k_scan1(const int* __restrict__ counts,
                                               int* __restrict__ pre,
                                               int* __restrict__ bsum, int n) {
    __shared__ int ws[4];
    int t = threadIdx.x, b = blockIdx.x, i = b * 256 + t;
    int lane = t & 63, w = t >> 6;
    int v = (i < n) ? counts[i] : 0;
    int x = v;
    #pragma unroll
    for (int off = 1; off < 64; off <<= 1) {
        int tt = __shfl_up(x, off);
        if (lane >= off) x += tt;
    }
    if (lane == 63) ws[w] = x;
    __syncthreads();
    int woff = 0;
    #pragma unroll
    for (int k = 0; k < 4; ++k) woff += (k < w) ? ws[k] : 0;
    int excl = x - v + woff;
    if (i < n) pre[i] = excl;
    if (t == 255) bsum[b] = excl + v;
}

// scan stage 2: single block scans block sums (nb <= 256); writes total to rp[n]
__global__ __launch_bounds__(256) void k_scan2(int* __restrict__ bsum,
                                               int* __restrict__ rp_end, int nb) {
    __shared__ int ws[4];
    int t = threadIdx.x;
    int lane = t & 63, w = t >> 6;
    int v = (t < nb) ? bsum[t] : 0;
    int x = v;
    #pragma unroll
    for (int off = 1; off < 64; off <<= 1) {
        int tt = __shfl_up(x, off);
        if (lane >= off) x += tt;
    }
    if (lane == 63) ws[w] = x;
    __syncthreads();
    int woff = 0;
    #pragma unroll
    for (int k = 0; k < 4; ++k) woff += (k < w) ? ws[k] : 0;
    int excl = x - v + woff;
    __syncthreads();
    if (t < nb) bsum[t] = excl;
    if (t == 255) *rp_end = excl + v;   // grand total = NEDGES
}

// scan stage 3: add block offsets; write row_ptr and cursor copy
__global__ __launch_bounds__(256) void k_scan3(int* __restrict__ rp,
                                               const int* __restrict__ bsum,
                                               int* __restrict__ cursor, int n) {
    int i = blockIdx.x * 256 + threadIdx.x;
    if (i < n) {
        int r = rp[i] + bsum[i >> 8];
        rp[i] = r;
        cursor[i] = r;
    }
}

// partition-owned scatter: partition p = blockIdx&7 owns dst in [p*npp,(p+1)*npp)
__global__ __launch_bounds__(256) void k_scatter_part(
    const int* __restrict__ src, const int* __restrict__ dst,
    int* __restrict__ cursor, int* __restrict__ csr_src, int n, int npp) {
    int part = blockIdx.x & (NPART - 1);
    int bip  = blockIdx.x >> 3;
    int nblk = gridDim.x >> 3;
    int lo = part * npp, hi = lo + npp;
    for (int i = bip * 256 + threadIdx.x; i < n; i += nblk * 256) {
        int d = dst[i];
        if (d >= lo && d < hi) {
            int p = atomicAdd(&cursor[d], 1);
            csr_src[p] = src[i];
        }
    }
}

// ---------------------------------------------------------------------------
// W [K][128] f32 -> Wt [128][K] bf16
// ---------------------------------------------------------------------------
__global__ void k_wt(const float* __restrict__ W, __bf16* __restrict__ Wt, int K) {
    int i = blockIdx.x * blockDim.x + threadIdx.x;
    if (i >= K * 128) return;
    int k = i >> 7, c = i & 127;
    Wt[(size_t)c * K + k] = (__bf16)W[i];
}

// ---------------------------------------------------------------------------
// MFMA bf16 GEMM, N=128, fused attention-score epilogue.
// AF32: A is fp32 (converted during LDS staging); else bf16.
// ---------------------------------------------------------------------------
template<bool AF32>
__global__ __launch_bounds__(256) void gemm_mfma_128(
    const void* __restrict__ Av, const __bf16* __restrict__ Wt,
    const float* __restrict__ al, const float* __restrict__ ar,
    __bf16* __restrict__ z, float* __restrict__ el, float* __restrict__ er,
    int M, int K)
{
    __shared__ alignas(16) __bf16 As[64 * 40];
    __shared__ alignas(16) __bf16 Bs[128 * 40];
    int tid = threadIdx.x;
    int wv = tid >> 6, l = tid & 63;
    int lr = l & 15, lk = l >> 4;
    int m0 = blockIdx.x * 64;
    f32x4 acc[8];
    f32x4 zero4 = {0.f, 0.f, 0.f, 0.f};
    #pragma unroll
    for (int nt = 0; nt < 8; ++nt) acc[nt] = zero4;

    int ar_ = tid >> 2, aq = tid & 3;
    for (int k0 = 0; k0 < K; k0 += 32) {
        {   // A tile: 64 x 32 bf16
            int m = m0 + ar_;
            if constexpr (AF32) {
                const float* A = (const float*)Av;
                __bf16 t8[8] = {};
                if (m < M) {
                    const float4* p = reinterpret_cast<const float4*>(&A[(size_t)m * K + k0 + aq * 8]);
                    float4 a = p[0], b = p[1];
                    t8[0] = (__bf16)a.x; t8[1] = (__bf16)a.y; t8[2] = (__bf16)a.z; t8[3] = (__bf16)a.w;
                    t8[4] = (__bf16)b.x; t8[5] = (__bf16)b.y; t8[6] = (__bf16)b.z; t8[7] = (__bf16)b.w;
                }
                *reinterpret_cast<uint4*>(&As[ar_ * 40 + aq * 8]) = *reinterpret_cast<uint4*>(t8);
            } else {
                const __bf16* A = (const __bf16*)Av;
                uint4 av = make_uint4(0, 0, 0, 0);
                if (m < M) av = *reinterpret_cast<const uint4*>(&A[(size_t)m * K + k0 + aq * 8]);
                *reinterpret_cast<uint4*>(&As[ar_ * 40 + aq * 8]) = av;
            }
        }
        {   // B tile: Wt rows (col-major W): 128 x 32 bf16
            #pragma unroll
            for (int t = 0; t < 2; ++t) {
                int cid = tid + t * 256;
                int c = cid >> 2, q = cid & 3;
                *reinterpret_cast<uint4*>(&Bs[c * 40 + q * 8]) =
                    *reinterpret_cast<const uint4*>(&Wt[(size_t)c * K + k0 + q * 8]);
            }
        }
        __syncthreads();
        bf16x8 af = *reinterpret_cast<const bf16x8*>(&As[(wv * 16 + lr) * 40 + lk * 8]);
        #pragma unroll
        for (int nt = 0; nt < 8; ++nt) {
            bf16x8 bfr = *reinterpret_cast<const bf16x8*>(&Bs[(nt * 16 + lr) * 40 + lk * 8]);
            acc[nt] = __builtin_amdgcn_mfma_f32_16x16x32_bf16(af, bfr, acc[nt], 0, 0, 0);
        }
        __syncthreads();
    }

    float alv[8], arv[8];
    #pragma unroll
    for (int nt = 0; nt < 8; ++nt) {
        alv[nt] = al[nt * 16 + lr];
        arv[nt] = ar[nt * 16 + lr];
    }
    #pragma unroll
    for (int r = 0; r < 4; ++r) {
        int m = m0 + wv * 16 + lk * 4 + r;   // C/D: row=(lane>>4)*4+reg, col=lane&15
        float pel[4], per_[4];
        #pragma unroll
        for (int h = 0; h < 4; ++h) {
            pel[h]  = acc[2 * h][r] * alv[2 * h] + acc[2 * h + 1][r] * alv[2 * h + 1];
            per_[h] = acc[2 * h][r] * arv[2 * h] + acc[2 * h + 1][r] * arv[2 * h + 1];
        }
        #pragma unroll
        for (int mk = 1; mk < 16; mk <<= 1) {
            #pragma unroll
            for (int h = 0; h < 4; ++h) {
                pel[h]  += __shfl_xor(pel[h], mk);
                per_[h] += __shfl_xor(per_[h], mk);
            }
        }
        if (m < M) {
            #pragma unroll
            for (int nt = 0; nt < 8; ++nt)
                z[(size_t)m * 128 + nt * 16 + lr] = (__bf16)acc[nt][r];
            if (lr == 0) {
                #pragma unroll
                for (int h = 0; h < 4; ++h) {
                    el[m * 4 + h] = pel[h];
                    er[m * 4 + h] = per_[h];
                }
            }
        }
    }
}

// ---------------------------------------------------------------------------
// chunk-parallel edge-softmax + aggregation, layers 1-2 (H=4, F=32)
// ---------------------------------------------------------------------------
__global__ __launch_bounds__(128) void gat_agg128c(
    const __bf16* __restrict__ z, const float* __restrict__ el,
    const float* __restrict__ er, const int* __restrict__ rp,
    const int* __restrict__ cs, const float* __restrict__ bias,
    __bf16* __restrict__ hout, int n_nodes)
{
    __shared__ uint2 sh[4][32];
    int nd = blockIdx.x;
    if (nd >= n_nodes) return;
    int t = threadIdx.x;
    int h = t >> 5, f = t & 31;
    int beg = rp[nd], end = rp[nd + 1];
    float erv = er[nd * 4 + h];
    float m = -3.0e38f, s = 0.f, acc = 0.f;
    const int zoff = h * 32 + f;

    for (int c0 = beg; c0 < end; c0 += 32) {
        int ch = end - c0; if (ch > 32) ch = 32;
        int chp = (ch + 7) & ~7;
        int sidx = (f < ch) ? cs[c0 + f] : 0;
        float e = -3.0e38f;
        if (f < ch) {
            float ev = el[sidx * 4 + h] + erv;
            e = (ev > 0.f) ? ev : 0.2f * ev;
        }
        float cm = e;
        #pragma unroll
        for (int mk = 16; mk; mk >>= 1) cm = fmaxf(cm, __shfl_xor(cm, mk));
        float nm = fmaxf(m, cm);
        float p = (f < ch) ? __expf(e - nm) : 0.f;
        float ps = p;
        #pragma unroll
        for (int mk = 16; mk; mk >>= 1) ps += __shfl_xor(ps, mk);
        float so = __expf(m - nm);
        s = s * so + ps;
        acc *= so;
        m = nm;
        sh[h][f] = make_uint2((unsigned)(sidx << 7), __float_as_uint(p));
        for (int k = 0; k < chp; k += 8) {
            float zv[8], pk[8];
            #pragma unroll
            for (int u = 0; u < 8; ++u) {
                uint2 v = sh[h][k + u];
                pk[u] = __uint_as_float(v.y);
                zv[u] = (float)z[(size_t)v.x + zoff];
            }
            #pragma unroll
            for (int u = 0; u < 8; ++u) acc += pk[u] * zv[u];
        }
    }
    float o = (end > beg) ? acc / s : 0.f;
    o += bias[zoff];
    o = fmaxf(o, 0.f);   // relu (layers 1-2)
    hout[(size_t)nd * 128 + zoff] = (__bf16)o;
}

// ---------------------------------------------------------------------------
// layer-3 GEMM (N=40) from bf16 input + fused el/er; z40 rows padded to 64
// ---------------------------------------------------------------------------
__global__ __launch_bounds__(256) void gemm40_attn(
    const __bf16* __restrict__ A, const float* __restrict__ W,
    const float* __restrict__ al, const float* __restrict__ arr,
    __bf16* __restrict__ z40, float* __restrict__ el3, float* __restrict__ er3,
    int M)
{
    __shared__ float Wl[128 * 40];
    __shared__ float rows[4][128];
    int tid = threadIdx.x, wid = tid >> 6, lane = tid & 63;
    int m = blockIdx.x * 4 + wid;
    for (int j = tid; j < 128 * 40; j += 256) Wl[j] = W[j];
    if (m < M && lane < 32) {
        const __bf16* ap = &A[(size_t)m * 128 + lane * 4];
        #pragma unroll
        for (int i = 0; i < 4; ++i) rows[wid][lane * 4 + i] = (float)ap[i];
    }
    __syncthreads();
    if (m >= M) return;
    bool act = lane < 40;
    float o = 0.f;
    if (act) {
        #pragma unroll 8
        for (int k = 0; k < 128; ++k) o += rows[wid][k] * Wl[k * 40 + lane];
    }
    float a = act ? o * al[lane] : 0.f;
    float b = act ? o * arr[lane] : 0.f;
    #pragma unroll
    for (int off = 32; off > 0; off >>= 1) {
        a += __shfl_xor(a, off);
        b += __shfl_xor(b, off);
    }
    if (act) z40[(size_t)m * 64 + lane] = (__bf16)o;
    if (lane == 0) { el3[m] = a; er3[m] = b; }
}

// ---------------------------------------------------------------------------
// layer-3 aggregation: chunk-parallel, 1 node per wave, + bias + log_softmax
// ---------------------------------------------------------------------------
__global__ __launch_bounds__(256) void gat_agg40c(
    const __bf16* __restrict__ z40, const float* __restrict__ el3,
    const float* __restrict__ er3, const int* __restrict__ rp,
    const int* __restrict__ cs, const float* __restrict__ bias,
    float* __restrict__ out, int n_nodes)
{
    __shared__ uint2 sh[4][64];
    int tid = threadIdx.x, wid = tid >> 6, lane = tid & 63;
    int nd = blockIdx.x * 4 + wid;
    if (nd >= n_nodes) return;
    bool act = lane < 40;
    int beg = rp[nd], end = rp[nd + 1];
    float erv = er3[nd];
    float m = -3.0e38f, s = 0.f, acc = 0.f;

    for (int c0 = beg; c0 < end; c0 += 64) {
        int ch = end - c0; if (ch > 64) ch = 64;
        int chp = (ch + 7) & ~7;
        int sidx = (lane < ch) ? cs[c0 + lane] : 0;
        float e = -3.0e38f;
        if (lane < ch) {
            float ev = el3[sidx] + erv;
            e = (ev > 0.f) ? ev : 0.2f * ev;
        }
        float cm = e;
        #pragma unroll
        for (int mk = 32; mk; mk >>= 1) cm = fmaxf(cm, __shfl_xor(cm, mk));
        float nm = fmaxf(m, cm);
        float p = (lane < ch) ? __expf(e - nm) : 0.f;
        float ps = p;
        #pragma unroll
        for (int mk = 32; mk; mk >>= 1) ps += __shfl_xor(ps, mk);
        float so = __expf(m - nm);
        s = s * so + ps;
        acc *= so;
        m = nm;
        sh[wid][lane] = make_uint2((unsigned)(sidx << 6), __float_as_uint(p));
        for (int k = 0; k < chp; k += 8) {
            float zv[8], pk[8];
            #pragma unroll
            for (int u = 0; u < 8; ++u) {
                uint2 v = sh[wid][k + u];
                pk[u] = __uint_as_float(v.y);
                zv[u] = (float)z40[(size_t)v.x + lane];
            }
            #pragma unroll
            for (int u = 0; u < 8; ++u) acc += pk[u] * zv[u];
        }
    }
    float o = (end > beg) ? acc / s : 0.f;
    o += act ? bias[lane] : 0.f;
    float v = act ? o : -3.0e38f;
    float mx = v;
    #pragma unroll
    for (int off = 32; off > 0; off >>= 1) mx = fmaxf(mx, __shfl_xor(mx, off));
    float p2 = act ? __expf(o - mx) : 0.f;
    float sum = p2;
    #pragma unroll
    for (int off = 32; off > 0; off >>= 1) sum += __shfl_xor(sum, off);
    if (act) out[(size_t)nd * 40 + lane] = o - mx - __logf(sum);
}

// ---------------------------------------------------------------------------
extern "C" void kernel_launch(void* const* d_in, const int* in_sizes, int n_in,
                              void* d_out, int out_size, void* d_ws, size_t ws_size,
                              hipStream_t stream) {
    const float* features = (const float*)d_in[0];
    const int*   src      = (const int*)d_in[1];
    const int*   dst      = (const int*)d_in[2];
    const float* W1  = (const float*)d_in[3];
    const float* al1 = (const float*)d_in[4];
    const float* ar1 = (const float*)d_in[5];
    const float* b1  = (const float*)d_in[6];
    const float* W2  = (const float*)d_in[7];
    const float* al2 = (const float*)d_in[8];
    const float* ar2 = (const float*)d_in[9];
    const float* b2  = (const float*)d_in[10];
    const float* W3  = (const float*)d_in[11];
    const float* al3 = (const float*)d_in[12];
    const float* ar3 = (const float*)d_in[13];
    const float* b3  = (const float*)d_in[14];
    float* out = (float*)d_out;

    const int N = NNODES, E = NEDGES;
    const int NB = (N + 255) / 256;   // scan blocks = 196

    // workspace layout (bytes)
    char* ws = (char*)d_ws;
    __bf16* z40    = (__bf16*)(ws + 0);            // N*64*2 = 6,400,000 (layer 3)
    __bf16* zb     = (__bf16*)(ws + 25600000);     // N*128*2
    __bf16* hb     = (__bf16*)(ws + 38400000);     // N*128*2
    float*  elb    = (float*)(ws + 51200000);      // N*4*4
    float*  erb    = (float*)(ws + 52000000);      // N*4*4
    __bf16* Wt1    = (__bf16*)(ws + 52800000);     // 128*256*2
    __bf16* Wt2    = (__bf16*)(ws + 52865536);     // 128*128*2
    int* row_ptr   = (int*)(ws + 52898304);        // (N+1)*4
    int* cursor    = (int*)(ws + 53098496);        // N*4
    int* csr_src   = (int*)(ws + 53298496);        // E*4
    int* bsum      = (int*)(ws + 56498496);        // 256*4 -> ends 56,499,520

    // ---- CSR build ----
    hipMemsetAsync(cursor, 0, (size_t)N * 4, stream);
    k_hist<<<(E + 255) / 256, 256, 0, stream>>>(dst, cursor, E);
    k_scan1<<<NB, 256, 0, stream>>>(cursor, row_ptr, bsum, N);
    k_scan2<<<1, 256, 0, stream>>>(bsum, &row_ptr[N], NB);
    k_scan3<<<NB, 256, 0, stream>>>(row_ptr, bsum, cursor, N);
    k_scatter_part<<<1024, 256, 0, stream>>>(src, dst, cursor, csr_src, E, N / NPART);

    // ---- weight converts ----
    k_wt<<<(256 * 128 + 255) / 256, 256, 0, stream>>>(W1, Wt1, 256);
    k_wt<<<(128 * 128 + 255) / 256, 256, 0, stream>>>(W2, Wt2, 128);

    // ---- layer 1 (A = fp32 features, converted in staging) ----
    gemm_mfma_128<true><<<(N + 63) / 64, 256, 0, stream>>>(features, Wt1, al1, ar1, zb, elb, erb, N, 256);
    gat_agg128c<<<N, 128, 0, stream>>>(zb, elb, erb, row_ptr, csr_src, b1, hb, N);

    // ---- layer 2 ----
    gemm_mfma_128<false><<<(N + 63) / 64, 256, 0, stream>>>(hb, Wt2, al2, ar2, zb, elb, erb, N, 128);
    gat_agg128c<<<N, 128, 0, stream>>>(zb, elb, erb, row_ptr, csr_src, b2, hb, N);

    // ---- layer 3 ----
    gemm40_attn<<<(N + 3) / 4, 256, 0, stream>>>(hb, W3, al3, ar3, z40, elb, erb, N);
    gat_agg40c<<<(N + 3) / 4, 256, 0, stream>>>(z40, elb, erb, row_ptr, csr_src, b3, out, N);

    (void)in_sizes; (void)n_in; (void)out_size; (void)ws_size;
}

// Round 5
// 253.551 us; speedup vs baseline: 2.4744x; 1.1480x over previous
//
#include <hip/hip_runtime.h>
#include <hip/hip_bf16.h>
#include <math.h>

// Problem constants (GAT_66907000537778)
#define NNODES 50000
#define NEDGES 800000
#define FIN 256
#define HID 32
#define HEADS 4
#define OUTS 40
#define HIDDEN 128   // HEADS*HID
#define NPART 8      // scatter partitions (dst ranges); 50000/8 = 6250

typedef __bf16 bf16x8 __attribute__((ext_vector_type(8)));
typedef float  f32x4  __attribute__((ext_vector_type(4)));

// ---------------------------------------------------------------------------
// CSR construction (grouped by dst)
// ---------------------------------------------------------------------------
__global__ void k_hist(const int* __restrict__ dst, int* __restrict__ counts, int n) {
    int i = blockIdx.x * blockDim.x + threadIdx.x;
    if (i < n) atomicAdd(&counts[dst[i]], 1);
}

__global__ __launch_bounds__(256) void k_scan1(const int* __restrict__ counts,
                                               int* __restrict__ pre,
                                               int* __restrict__ bsum, int n) {
    __shared__ int ws[4];
    int t = threadIdx.x, b = blockIdx.x, i = b * 256 + t;
    int lane = t & 63, w = t >> 6;
    int v = (i < n) ? counts[i] : 0;
    int x = v;
    #pragma unroll
    for (int off = 1; off < 64; off <<= 1) {
        int tt = __shfl_up(x, off);
        if (lane >= off) x += tt;
    }
    if (lane == 63) ws[w] = x;
    __syncthreads();
    int woff = 0;
    #pragma unroll
    for (int k = 0; k < 4; ++k) woff += (k < w) ? ws[k] : 0;
    int excl = x - v + woff;
    if (i < n) pre[i] = excl;
    if (t == 255) bsum[b] = excl + v;
}

__global__ __launch_bounds__(256) void k_scan2(int* __restrict__ bsum,
                                               int* __restrict__ rp_end, int nb) {
    __shared__ int ws[4];
    int t = threadIdx.x;
    int lane = t & 63, w = t >> 6;
    int v = (t < nb) ? bsum[t] : 0;
    int x = v;
    #pragma unroll
    for (int off = 1; off < 64; off <<= 1) {
        int tt = __shfl_up(x, off);
        if (lane >= off) x += tt;
    }
    if (lane == 63) ws[w] = x;
    __syncthreads();
    int woff = 0;
    #pragma unroll
    for (int k = 0; k < 4; ++k) woff += (k < w) ? ws[k] : 0;
    int excl = x - v + woff;
    __syncthreads();
    if (t < nb) bsum[t] = excl;
    if (t == 255) *rp_end = excl + v;   // grand total = NEDGES
}

__global__ __launch_bounds__(256) void k_scan3(int* __restrict__ rp,
                                               const int* __restrict__ bsum,
                                               int* __restrict__ cursor, int n) {
    int i = blockIdx.x * 256 + threadIdx.x;
    if (i < n) {
        int r = rp[i] + bsum[i >> 8];
        rp[i] = r;
        cursor[i] = r;
    }
}

__global__ __launch_bounds__(256) void k_scatter_part(
    const int* __restrict__ src, const int* __restrict__ dst,
    int* __restrict__ cursor, int* __restrict__ csr_src, int n, int npp) {
    int part = blockIdx.x & (NPART - 1);
    int bip  = blockIdx.x >> 3;
    int nblk = gridDim.x >> 3;
    int lo = part * npp, hi = lo + npp;
    for (int i = bip * 256 + threadIdx.x; i < n; i += nblk * 256) {
        int d = dst[i];
        if (d >= lo && d < hi) {
            int p = atomicAdd(&cursor[d], 1);
            csr_src[p] = src[i];
        }
    }
}

// ---------------------------------------------------------------------------
// weight transposes/converts
// ---------------------------------------------------------------------------
// W [K][128] f32 -> Wt [128][K] bf16
__global__ void k_wt(const float* __restrict__ W, __bf16* __restrict__ Wt, int K) {
    int i = blockIdx.x * blockDim.x + threadIdx.x;
    if (i >= K * 128) return;
    int k = i >> 7, c = i & 127;
    Wt[(size_t)c * K + k] = (__bf16)W[i];
}

// W3 [128][40] f32 -> Wt3 [48][128] bf16 (rows 40..47 zero)
__global__ void k_wt3(const float* __restrict__ W, __bf16* __restrict__ Wt) {
    int i = blockIdx.x * blockDim.x + threadIdx.x;
    if (i >= 48 * 128) return;
    int c = i >> 7, k = i & 127;
    Wt[(size_t)c * 128 + k] = (c < 40) ? (__bf16)W[(size_t)k * 40 + c] : (__bf16)0.f;
}

// ---------------------------------------------------------------------------
// MFMA bf16 GEMM, N=128, fused attention-score epilogue.
// AF32: A is fp32 (converted during LDS staging); else bf16.
// ---------------------------------------------------------------------------
template<bool AF32>
__global__ __launch_bounds__(256) void gemm_mfma_128(
    const void* __restrict__ Av, const __bf16* __restrict__ Wt,
    const float* __restrict__ al, const float* __restrict__ ar,
    __bf16* __restrict__ z, float* __restrict__ el, float* __restrict__ er,
    int M, int K)
{
    __shared__ alignas(16) __bf16 As[64 * 40];
    __shared__ alignas(16) __bf16 Bs[128 * 40];
    int tid = threadIdx.x;
    int wv = tid >> 6, l = tid & 63;
    int lr = l & 15, lk = l >> 4;
    int m0 = blockIdx.x * 64;
    f32x4 acc[8];
    f32x4 zero4 = {0.f, 0.f, 0.f, 0.f};
    #pragma unroll
    for (int nt = 0; nt < 8; ++nt) acc[nt] = zero4;

    int ar_ = tid >> 2, aq = tid & 3;
    for (int k0 = 0; k0 < K; k0 += 32) {
        {   // A tile: 64 x 32 bf16
            int m = m0 + ar_;
            if constexpr (AF32) {
                const float* A = (const float*)Av;
                __bf16 t8[8] = {};
                if (m < M) {
                    const float4* p = reinterpret_cast<const float4*>(&A[(size_t)m * K + k0 + aq * 8]);
                    float4 a = p[0], b = p[1];
                    t8[0] = (__bf16)a.x; t8[1] = (__bf16)a.y; t8[2] = (__bf16)a.z; t8[3] = (__bf16)a.w;
                    t8[4] = (__bf16)b.x; t8[5] = (__bf16)b.y; t8[6] = (__bf16)b.z; t8[7] = (__bf16)b.w;
                }
                *reinterpret_cast<uint4*>(&As[ar_ * 40 + aq * 8]) = *reinterpret_cast<uint4*>(t8);
            } else {
                const __bf16* A = (const __bf16*)Av;
                uint4 av = make_uint4(0, 0, 0, 0);
                if (m < M) av = *reinterpret_cast<const uint4*>(&A[(size_t)m * K + k0 + aq * 8]);
                *reinterpret_cast<uint4*>(&As[ar_ * 40 + aq * 8]) = av;
            }
        }
        {   // B tile: Wt rows (col-major W): 128 x 32 bf16
            #pragma unroll
            for (int t = 0; t < 2; ++t) {
                int cid = tid + t * 256;
                int c = cid >> 2, q = cid & 3;
                *reinterpret_cast<uint4*>(&Bs[c * 40 + q * 8]) =
                    *reinterpret_cast<const uint4*>(&Wt[(size_t)c * K + k0 + q * 8]);
            }
        }
        __syncthreads();
        bf16x8 af = *reinterpret_cast<const bf16x8*>(&As[(wv * 16 + lr) * 40 + lk * 8]);
        #pragma unroll
        for (int nt = 0; nt < 8; ++nt) {
            bf16x8 bfr = *reinterpret_cast<const bf16x8*>(&Bs[(nt * 16 + lr) * 40 + lk * 8]);
            acc[nt] = __builtin_amdgcn_mfma_f32_16x16x32_bf16(af, bfr, acc[nt], 0, 0, 0);
        }
        __syncthreads();
    }

    float alv[8], arv[8];
    #pragma unroll
    for (int nt = 0; nt < 8; ++nt) {
        alv[nt] = al[nt * 16 + lr];
        arv[nt] = ar[nt * 16 + lr];
    }
    #pragma unroll
    for (int r = 0; r < 4; ++r) {
        int m = m0 + wv * 16 + lk * 4 + r;   // C/D: row=(lane>>4)*4+reg, col=lane&15
        float pel[4], per_[4];
        #pragma unroll
        for (int h = 0; h < 4; ++h) {
            pel[h]  = acc[2 * h][r] * alv[2 * h] + acc[2 * h + 1][r] * alv[2 * h + 1];
            per_[h] = acc[2 * h][r] * arv[2 * h] + acc[2 * h + 1][r] * arv[2 * h + 1];
        }
        #pragma unroll
        for (int mk = 1; mk < 16; mk <<= 1) {
            #pragma unroll
            for (int h = 0; h < 4; ++h) {
                pel[h]  += __shfl_xor(pel[h], mk);
                per_[h] += __shfl_xor(per_[h], mk);
            }
        }
        if (m < M) {
            #pragma unroll
            for (int nt = 0; nt < 8; ++nt)
                z[(size_t)m * 128 + nt * 16 + lr] = (__bf16)acc[nt][r];
            if (lr == 0) {
                #pragma unroll
                for (int h = 0; h < 4; ++h) {
                    el[m * 4 + h] = pel[h];
                    er[m * 4 + h] = per_[h];
                }
            }
        }
    }
}

// ---------------------------------------------------------------------------
// layer-3 MFMA GEMM: z40[M,40(pad64)] = A[M,128] * W3[128,40], fused el3/er3.
// Tile 64(M) x 48(N) (cols 40..47 are zero-padded in Wt3), K=128.
// ---------------------------------------------------------------------------
__global__ __launch_bounds__(256) void gemm40_mfma(
    const __bf16* __restrict__ A, const __bf16* __restrict__ Wt3,
    const float* __restrict__ al, const float* __restrict__ arr,
    __bf16* __restrict__ z40, float* __restrict__ el3, float* __restrict__ er3,
    int M)
{
    __shared__ alignas(16) __bf16 As[64 * 40];
    __shared__ alignas(16) __bf16 Bs[48 * 40];
    int tid = threadIdx.x;
    int wv = tid >> 6, l = tid & 63;
    int lr = l & 15, lk = l >> 4;
    int m0 = blockIdx.x * 64;
    f32x4 acc[3];
    f32x4 zero4 = {0.f, 0.f, 0.f, 0.f};
    #pragma unroll
    for (int nt = 0; nt < 3; ++nt) acc[nt] = zero4;

    int ar_ = tid >> 2, aq = tid & 3;
    for (int k0 = 0; k0 < 128; k0 += 32) {
        {   // A tile: 64 x 32 bf16
            int m = m0 + ar_;
            uint4 av = make_uint4(0, 0, 0, 0);
            if (m < M) av = *reinterpret_cast<const uint4*>(&A[(size_t)m * 128 + k0 + aq * 8]);
            *reinterpret_cast<uint4*>(&As[ar_ * 40 + aq * 8]) = av;
        }
        if (tid < 192) {   // B tile: 48 x 32 bf16
            int c = tid >> 2, q = tid & 3;
            *reinterpret_cast<uint4*>(&Bs[c * 40 + q * 8]) =
                *reinterpret_cast<const uint4*>(&Wt3[(size_t)c * 128 + k0 + q * 8]);
        }
        __syncthreads();
        bf16x8 af = *reinterpret_cast<const bf16x8*>(&As[(wv * 16 + lr) * 40 + lk * 8]);
        #pragma unroll
        for (int nt = 0; nt < 3; ++nt) {
            bf16x8 bfr = *reinterpret_cast<const bf16x8*>(&Bs[(nt * 16 + lr) * 40 + lk * 8]);
            acc[nt] = __builtin_amdgcn_mfma_f32_16x16x32_bf16(af, bfr, acc[nt], 0, 0, 0);
        }
        __syncthreads();
    }

    float alv[3], arv[3];
    #pragma unroll
    for (int nt = 0; nt < 3; ++nt) {
        int col = nt * 16 + lr;
        alv[nt] = (col < 40) ? al[col] : 0.f;
        arv[nt] = (col < 40) ? arr[col] : 0.f;
    }
    #pragma unroll
    for (int r = 0; r < 4; ++r) {
        int m = m0 + wv * 16 + lk * 4 + r;
        float pel = acc[0][r] * alv[0] + acc[1][r] * alv[1] + acc[2][r] * alv[2];
        float per_ = acc[0][r] * arv[0] + acc[1][r] * arv[1] + acc[2][r] * arv[2];
        #pragma unroll
        for (int mk = 1; mk < 16; mk <<= 1) {
            pel  += __shfl_xor(pel, mk);
            per_ += __shfl_xor(per_, mk);
        }
        if (m < M) {
            #pragma unroll
            for (int nt = 0; nt < 3; ++nt) {
                int col = nt * 16 + lr;
                if (col < 40) z40[(size_t)m * 64 + col] = (__bf16)acc[nt][r];
            }
            if (lr == 0) { el3[m] = pel; er3[m] = per_; }
        }
    }
}

// ---------------------------------------------------------------------------
// chunk-parallel edge-softmax + aggregation, layers 1-2 (H=4, F=32)
// ---------------------------------------------------------------------------
__global__ __launch_bounds__(128) void gat_agg128c(
    const __bf16* __restrict__ z, const float* __restrict__ el,
    const float* __restrict__ er, const int* __restrict__ rp,
    const int* __restrict__ cs, const float* __restrict__ bias,
    __bf16* __restrict__ hout, int n_nodes)
{
    __shared__ uint2 sh[4][32];
    int nd = blockIdx.x;
    if (nd >= n_nodes) return;
    int t = threadIdx.x;
    int h = t >> 5, f = t & 31;
    int beg = rp[nd], end = rp[nd + 1];
    float erv = er[nd * 4 + h];
    float m = -3.0e38f, s = 0.f, acc = 0.f;
    const int zoff = h * 32 + f;

    for (int c0 = beg; c0 < end; c0 += 32) {
        int ch = end - c0; if (ch > 32) ch = 32;
        int chp = (ch + 7) & ~7;
        int sidx = (f < ch) ? cs[c0 + f] : 0;
        float e = -3.0e38f;
        if (f < ch) {
            float ev = el[sidx * 4 + h] + erv;
            e = (ev > 0.f) ? ev : 0.2f * ev;
        }
        float cm = e;
        #pragma unroll
        for (int mk = 16; mk; mk >>= 1) cm = fmaxf(cm, __shfl_xor(cm, mk));
        float nm = fmaxf(m, cm);
        float p = (f < ch) ? __expf(e - nm) : 0.f;
        float ps = p;
        #pragma unroll
        for (int mk = 16; mk; mk >>= 1) ps += __shfl_xor(ps, mk);
        float so = __expf(m - nm);
        s = s * so + ps;
        acc *= so;
        m = nm;
        sh[h][f] = make_uint2((unsigned)(sidx << 7), __float_as_uint(p));
        for (int k = 0; k < chp; k += 8) {
            float zv[8], pk[8];
            #pragma unroll
            for (int u = 0; u < 8; ++u) {
                uint2 v = sh[h][k + u];
                pk[u] = __uint_as_float(v.y);
                zv[u] = (float)z[(size_t)v.x + zoff];
            }
            #pragma unroll
            for (int u = 0; u < 8; ++u) acc += pk[u] * zv[u];
        }
    }
    float o = (end > beg) ? acc / s : 0.f;
    o += bias[zoff];
    o = fmaxf(o, 0.f);   // relu (layers 1-2)
    hout[(size_t)nd * 128 + zoff] = (__bf16)o;
}

// ---------------------------------------------------------------------------
// layer-3 aggregation: chunk-parallel, 1 node per wave, + bias + log_softmax
// ---------------------------------------------------------------------------
__global__ __launch_bounds__(256) void gat_agg40c(
    const __bf16* __restrict__ z40, const float* __restrict__ el3,
    const float* __restrict__ er3, const int* __restrict__ rp,
    const int* __restrict__ cs, const float* __restrict__ bias,
    float* __restrict__ out, int n_nodes)
{
    __shared__ uint2 sh[4][64];
    int tid = threadIdx.x, wid = tid >> 6, lane = tid & 63;
    int nd = blockIdx.x * 4 + wid;
    if (nd >= n_nodes) return;
    bool act = lane < 40;
    int beg = rp[nd], end = rp[nd + 1];
    float erv = er3[nd];
    float m = -3.0e38f, s = 0.f, acc = 0.f;

    for (int c0 = beg; c0 < end; c0 += 64) {
        int ch = end - c0; if (ch > 64) ch = 64;
        int chp = (ch + 7) & ~7;
        int sidx = (lane < ch) ? cs[c0 + lane] : 0;
        float e = -3.0e38f;
        if (lane < ch) {
            float ev = el3[sidx] + erv;
            e = (ev > 0.f) ? ev : 0.2f * ev;
        }
        float cm = e;
        #pragma unroll
        for (int mk = 32; mk; mk >>= 1) cm = fmaxf(cm, __shfl_xor(cm, mk));
        float nm = fmaxf(m, cm);
        float p = (lane < ch) ? __expf(e - nm) : 0.f;
        float ps = p;
        #pragma unroll
        for (int mk = 32; mk; mk >>= 1) ps += __shfl_xor(ps, mk);
        float so = __expf(m - nm);
        s = s * so + ps;
        acc *= so;
        m = nm;
        sh[wid][lane] = make_uint2((unsigned)(sidx << 6), __float_as_uint(p));
        for (int k = 0; k < chp; k += 8) {
            float zv[8], pk[8];
            #pragma unroll
            for (int u = 0; u < 8; ++u) {
                uint2 v = sh[wid][k + u];
                pk[u] = __uint_as_float(v.y);
                zv[u] = (float)z40[(size_t)v.x + lane];
            }
            #pragma unroll
            for (int u = 0; u < 8; ++u) acc += pk[u] * zv[u];
        }
    }
    float o = (end > beg) ? acc / s : 0.f;
    o += act ? bias[lane] : 0.f;
    float v = act ? o : -3.0e38f;
    float mx = v;
    #pragma unroll
    for (int off = 32; off > 0; off >>= 1) mx = fmaxf(mx, __shfl_xor(mx, off));
    float p2 = act ? __expf(o - mx) : 0.f;
    float sum = p2;
    #pragma unroll
    for (int off = 32; off > 0; off >>= 1) sum += __shfl_xor(sum, off);
    if (act) out[(size_t)nd * 40 + lane] = o - mx - __logf(sum);
}

// ---------------------------------------------------------------------------
extern "C" void kernel_launch(void* const* d_in, const int* in_sizes, int n_in,
                              void* d_out, int out_size, void* d_ws, size_t ws_size,
                              hipStream_t stream) {
    const float* features = (const float*)d_in[0];
    const int*   src      = (const int*)d_in[1];
    const int*   dst      = (const int*)d_in[2];
    const float* W1  = (const float*)d_in[3];
    const float* al1 = (const float*)d_in[4];
    const float* ar1 = (const float*)d_in[5];
    const float* b1  = (const float*)d_in[6];
    const float* W2  = (const float*)d_in[7];
    const float* al2 = (const float*)d_in[8];
    const float* ar2 = (const float*)d_in[9];
    const float* b2  = (const float*)d_in[10];
    const float* W3  = (const float*)d_in[11];
    const float* al3 = (const float*)d_in[12];
    const float* ar3 = (const float*)d_in[13];
    const float* b3  = (const float*)d_in[14];
    float* out = (float*)d_out;

    const int N = NNODES, E = NEDGES;
    const int NB = (N + 255) / 256;   // scan blocks = 196

    // workspace layout (bytes)
    char* ws = (char*)d_ws;
    __bf16* z40    = (__bf16*)(ws + 0);            // N*64*2 = 6,400,000 (layer 3)
    __bf16* Wt3    = (__bf16*)(ws + 6400000);      // 48*128*2 = 12,288
    __bf16* zb     = (__bf16*)(ws + 25600000);     // N*128*2
    __bf16* hb     = (__bf16*)(ws + 38400000);     // N*128*2
    float*  elb    = (float*)(ws + 51200000);      // N*4*4
    float*  erb    = (float*)(ws + 52000000);      // N*4*4
    __bf16* Wt1    = (__bf16*)(ws + 52800000);     // 128*256*2
    __bf16* Wt2    = (__bf16*)(ws + 52865536);     // 128*128*2
    int* row_ptr   = (int*)(ws + 52898304);        // (N+1)*4
    int* cursor    = (int*)(ws + 53098496);        // N*4
    int* csr_src   = (int*)(ws + 53298496);        // E*4
    int* bsum      = (int*)(ws + 56498496);        // 256*4 -> ends 56,499,520

    // ---- CSR build ----
    hipMemsetAsync(cursor, 0, (size_t)N * 4, stream);
    k_hist<<<(E + 255) / 256, 256, 0, stream>>>(dst, cursor, E);
    k_scan1<<<NB, 256, 0, stream>>>(cursor, row_ptr, bsum, N);
    k_scan2<<<1, 256, 0, stream>>>(bsum, &row_ptr[N], NB);
    k_scan3<<<NB, 256, 0, stream>>>(row_ptr, bsum, cursor, N);
    k_scatter_part<<<1024, 256, 0, stream>>>(src, dst, cursor, csr_src, E, N / NPART);

    // ---- weight converts ----
    k_wt<<<(256 * 128 + 255) / 256, 256, 0, stream>>>(W1, Wt1, 256);
    k_wt<<<(128 * 128 + 255) / 256, 256, 0, stream>>>(W2, Wt2, 128);
    k_wt3<<<(48 * 128 + 255) / 256, 256, 0, stream>>>(W3, Wt3);

    // ---- layer 1 (A = fp32 features, converted in staging) ----
    gemm_mfma_128<true><<<(N + 63) / 64, 256, 0, stream>>>(features, Wt1, al1, ar1, zb, elb, erb, N, 256);
    gat_agg128c<<<N, 128, 0, stream>>>(zb, elb, erb, row_ptr, csr_src, b1, hb, N);

    // ---- layer 2 ----
    gemm_mfma_128<false><<<(N + 63) / 64, 256, 0, stream>>>(hb, Wt2, al2, ar2, zb, elb, erb, N, 128);
    gat_agg128c<<<N, 128, 0, stream>>>(zb, elb, erb, row_ptr, csr_src, b2, hb, N);

    // ---- layer 3 ----
    gemm40_mfma<<<(N + 63) / 64, 256, 0, stream>>>(hb, Wt3, al3, ar3, z40, elb, erb, N);
    gat_agg40c<<<(N + 3) / 4, 256, 0, stream>>>(z40, elb, erb, row_ptr, csr_src, b3, out, N);

    (void)in_sizes; (void)n_in; (void)out_size; (void)ws_size;
}

// Round 6
// 240.067 us; speedup vs baseline: 2.6134x; 1.0562x over previous
//
#include <hip/hip_runtime.h>
#include <hip/hip_bf16.h>
#include <math.h>

// Problem constants (GAT_66907000537778)
#define NNODES 50000
#define NEDGES 800000
#define FIN 256
#define HID 32
#define HEADS 4
#define OUTS 40
#define HIDDEN 128   // HEADS*HID
#define NPART 8      // scatter partitions (dst ranges); 50000/8 = 6250

typedef __bf16 bf16x8 __attribute__((ext_vector_type(8)));
typedef float  f32x4  __attribute__((ext_vector_type(4)));

// ---------------------------------------------------------------------------
// CSR construction (grouped by dst)
// ---------------------------------------------------------------------------
__global__ void k_hist(const int* __restrict__ dst, int* __restrict__ counts, int n) {
    int i = blockIdx.x * blockDim.x + threadIdx.x;
    if (i < n) atomicAdd(&counts[dst[i]], 1);
}

__global__ __launch_bounds__(256) void k_scan1(const int* __restrict__ counts,
                                               int* __restrict__ pre,
                                               int* __restrict__ bsum, int n) {
    __shared__ int ws[4];
    int t = threadIdx.x, b = blockIdx.x, i = b * 256 + t;
    int lane = t & 63, w = t >> 6;
    int v = (i < n) ? counts[i] : 0;
    int x = v;
    #pragma unroll
    for (int off = 1; off < 64; off <<= 1) {
        int tt = __shfl_up(x, off);
        if (lane >= off) x += tt;
    }
    if (lane == 63) ws[w] = x;
    __syncthreads();
    int woff = 0;
    #pragma unroll
    for (int k = 0; k < 4; ++k) woff += (k < w) ? ws[k] : 0;
    int excl = x - v + woff;
    if (i < n) pre[i] = excl;
    if (t == 255) bsum[b] = excl + v;
}

__global__ __launch_bounds__(256) void k_scan2(int* __restrict__ bsum,
                                               int* __restrict__ rp_end, int nb) {
    __shared__ int ws[4];
    int t = threadIdx.x;
    int lane = t & 63, w = t >> 6;
    int v = (t < nb) ? bsum[t] : 0;
    int x = v;
    #pragma unroll
    for (int off = 1; off < 64; off <<= 1) {
        int tt = __shfl_up(x, off);
        if (lane >= off) x += tt;
    }
    if (lane == 63) ws[w] = x;
    __syncthreads();
    int woff = 0;
    #pragma unroll
    for (int k = 0; k < 4; ++k) woff += (k < w) ? ws[k] : 0;
    int excl = x - v + woff;
    __syncthreads();
    if (t < nb) bsum[t] = excl;
    if (t == 255) *rp_end = excl + v;   // grand total = NEDGES
}

__global__ __launch_bounds__(256) void k_scan3(int* __restrict__ rp,
                                               const int* __restrict__ bsum,
                                               int* __restrict__ cursor, int n) {
    int i = blockIdx.x * 256 + threadIdx.x;
    if (i < n) {
        int r = rp[i] + bsum[i >> 8];
        rp[i] = r;
        cursor[i] = r;
    }
}

__global__ __launch_bounds__(256) void k_scatter_part(
    const int* __restrict__ src, const int* __restrict__ dst,
    int* __restrict__ cursor, int* __restrict__ csr_src, int n, int npp) {
    int part = blockIdx.x & (NPART - 1);
    int bip  = blockIdx.x >> 3;
    int nblk = gridDim.x >> 3;
    int lo = part * npp, hi = lo + npp;
    for (int i = bip * 256 + threadIdx.x; i < n; i += nblk * 256) {
        int d = dst[i];
        if (d >= lo && d < hi) {
            int p = atomicAdd(&cursor[d], 1);
            csr_src[p] = src[i];
        }
    }
}

// ---------------------------------------------------------------------------
// weight transposes/converts
// ---------------------------------------------------------------------------
// W [K][128] f32 -> Wt [128][K] bf16
__global__ void k_wt(const float* __restrict__ W, __bf16* __restrict__ Wt, int K) {
    int i = blockIdx.x * blockDim.x + threadIdx.x;
    if (i >= K * 128) return;
    int k = i >> 7, c = i & 127;
    Wt[(size_t)c * K + k] = (__bf16)W[i];
}

// W3 [128][40] f32 -> Wt3 [48][128] bf16 (rows 40..47 zero)
__global__ void k_wt3(const float* __restrict__ W, __bf16* __restrict__ Wt) {
    int i = blockIdx.x * blockDim.x + threadIdx.x;
    if (i >= 48 * 128) return;
    int c = i >> 7, k = i & 127;
    Wt[(size_t)c * 128 + k] = (c < 40) ? (__bf16)W[(size_t)k * 40 + c] : (__bf16)0.f;
}

// ---------------------------------------------------------------------------
// MFMA bf16 GEMM, N=128, fused attention-score epilogue.
// AF32: A is fp32 (converted during LDS staging); else bf16.
// ---------------------------------------------------------------------------
template<bool AF32>
__global__ __launch_bounds__(256) void gemm_mfma_128(
    const void* __restrict__ Av, const __bf16* __restrict__ Wt,
    const float* __restrict__ al, const float* __restrict__ ar,
    __bf16* __restrict__ z, float* __restrict__ el, float* __restrict__ er,
    int M, int K)
{
    __shared__ alignas(16) __bf16 As[64 * 40];
    __shared__ alignas(16) __bf16 Bs[128 * 40];
    int tid = threadIdx.x;
    int wv = tid >> 6, l = tid & 63;
    int lr = l & 15, lk = l >> 4;
    int m0 = blockIdx.x * 64;
    f32x4 acc[8];
    f32x4 zero4 = {0.f, 0.f, 0.f, 0.f};
    #pragma unroll
    for (int nt = 0; nt < 8; ++nt) acc[nt] = zero4;

    int ar_ = tid >> 2, aq = tid & 3;
    for (int k0 = 0; k0 < K; k0 += 32) {
        {   // A tile: 64 x 32 bf16
            int m = m0 + ar_;
            if constexpr (AF32) {
                const float* A = (const float*)Av;
                __bf16 t8[8] = {};
                if (m < M) {
                    const float4* p = reinterpret_cast<const float4*>(&A[(size_t)m * K + k0 + aq * 8]);
                    float4 a = p[0], b = p[1];
                    t8[0] = (__bf16)a.x; t8[1] = (__bf16)a.y; t8[2] = (__bf16)a.z; t8[3] = (__bf16)a.w;
                    t8[4] = (__bf16)b.x; t8[5] = (__bf16)b.y; t8[6] = (__bf16)b.z; t8[7] = (__bf16)b.w;
                }
                *reinterpret_cast<uint4*>(&As[ar_ * 40 + aq * 8]) = *reinterpret_cast<uint4*>(t8);
            } else {
                const __bf16* A = (const __bf16*)Av;
                uint4 av = make_uint4(0, 0, 0, 0);
                if (m < M) av = *reinterpret_cast<const uint4*>(&A[(size_t)m * K + k0 + aq * 8]);
                *reinterpret_cast<uint4*>(&As[ar_ * 40 + aq * 8]) = av;
            }
        }
        {   // B tile: Wt rows (col-major W): 128 x 32 bf16
            #pragma unroll
            for (int t = 0; t < 2; ++t) {
                int cid = tid + t * 256;
                int c = cid >> 2, q = cid & 3;
                *reinterpret_cast<uint4*>(&Bs[c * 40 + q * 8]) =
                    *reinterpret_cast<const uint4*>(&Wt[(size_t)c * K + k0 + q * 8]);
            }
        }
        __syncthreads();
        bf16x8 af = *reinterpret_cast<const bf16x8*>(&As[(wv * 16 + lr) * 40 + lk * 8]);
        #pragma unroll
        for (int nt = 0; nt < 8; ++nt) {
            bf16x8 bfr = *reinterpret_cast<const bf16x8*>(&Bs[(nt * 16 + lr) * 40 + lk * 8]);
            acc[nt] = __builtin_amdgcn_mfma_f32_16x16x32_bf16(af, bfr, acc[nt], 0, 0, 0);
        }
        __syncthreads();
    }

    float alv[8], arv[8];
    #pragma unroll
    for (int nt = 0; nt < 8; ++nt) {
        alv[nt] = al[nt * 16 + lr];
        arv[nt] = ar[nt * 16 + lr];
    }
    #pragma unroll
    for (int r = 0; r < 4; ++r) {
        int m = m0 + wv * 16 + lk * 4 + r;   // C/D: row=(lane>>4)*4+reg, col=lane&15
        float pel[4], per_[4];
        #pragma unroll
        for (int h = 0; h < 4; ++h) {
            pel[h]  = acc[2 * h][r] * alv[2 * h] + acc[2 * h + 1][r] * alv[2 * h + 1];
            per_[h] = acc[2 * h][r] * arv[2 * h] + acc[2 * h + 1][r] * arv[2 * h + 1];
        }
        #pragma unroll
        for (int mk = 1; mk < 16; mk <<= 1) {
            #pragma unroll
            for (int h = 0; h < 4; ++h) {
                pel[h]  += __shfl_xor(pel[h], mk);
                per_[h] += __shfl_xor(per_[h], mk);
            }
        }
        if (m < M) {
            #pragma unroll
            for (int nt = 0; nt < 8; ++nt)
                z[(size_t)m * 128 + nt * 16 + lr] = (__bf16)acc[nt][r];
            if (lr == 0) {
                #pragma unroll
                for (int h = 0; h < 4; ++h) {
                    el[m * 4 + h] = pel[h];
                    er[m * 4 + h] = per_[h];
                }
            }
        }
    }
}

// ---------------------------------------------------------------------------
// layer-3 MFMA GEMM: z40[M,40(pad64)] = A[M,128] * W3[128,40], fused el3/er3.
// ---------------------------------------------------------------------------
__global__ __launch_bounds__(256) void gemm40_mfma(
    const __bf16* __restrict__ A, const __bf16* __restrict__ Wt3,
    const float* __restrict__ al, const float* __restrict__ arr,
    __bf16* __restrict__ z40, float* __restrict__ el3, float* __restrict__ er3,
    int M)
{
    __shared__ alignas(16) __bf16 As[64 * 40];
    __shared__ alignas(16) __bf16 Bs[48 * 40];
    int tid = threadIdx.x;
    int wv = tid >> 6, l = tid & 63;
    int lr = l & 15, lk = l >> 4;
    int m0 = blockIdx.x * 64;
    f32x4 acc[3];
    f32x4 zero4 = {0.f, 0.f, 0.f, 0.f};
    #pragma unroll
    for (int nt = 0; nt < 3; ++nt) acc[nt] = zero4;

    int ar_ = tid >> 2, aq = tid & 3;
    for (int k0 = 0; k0 < 128; k0 += 32) {
        {   // A tile: 64 x 32 bf16
            int m = m0 + ar_;
            uint4 av = make_uint4(0, 0, 0, 0);
            if (m < M) av = *reinterpret_cast<const uint4*>(&A[(size_t)m * 128 + k0 + aq * 8]);
            *reinterpret_cast<uint4*>(&As[ar_ * 40 + aq * 8]) = av;
        }
        if (tid < 192) {   // B tile: 48 x 32 bf16
            int c = tid >> 2, q = tid & 3;
            *reinterpret_cast<uint4*>(&Bs[c * 40 + q * 8]) =
                *reinterpret_cast<const uint4*>(&Wt3[(size_t)c * 128 + k0 + q * 8]);
        }
        __syncthreads();
        bf16x8 af = *reinterpret_cast<const bf16x8*>(&As[(wv * 16 + lr) * 40 + lk * 8]);
        #pragma unroll
        for (int nt = 0; nt < 3; ++nt) {
            bf16x8 bfr = *reinterpret_cast<const bf16x8*>(&Bs[(nt * 16 + lr) * 40 + lk * 8]);
            acc[nt] = __builtin_amdgcn_mfma_f32_16x16x32_bf16(af, bfr, acc[nt], 0, 0, 0);
        }
        __syncthreads();
    }

    float alv[3], arv[3];
    #pragma unroll
    for (int nt = 0; nt < 3; ++nt) {
        int col = nt * 16 + lr;
        alv[nt] = (col < 40) ? al[col] : 0.f;
        arv[nt] = (col < 40) ? arr[col] : 0.f;
    }
    #pragma unroll
    for (int r = 0; r < 4; ++r) {
        int m = m0 + wv * 16 + lk * 4 + r;
        float pel = acc[0][r] * alv[0] + acc[1][r] * alv[1] + acc[2][r] * alv[2];
        float per_ = acc[0][r] * arv[0] + acc[1][r] * arv[1] + acc[2][r] * arv[2];
        #pragma unroll
        for (int mk = 1; mk < 16; mk <<= 1) {
            pel  += __shfl_xor(pel, mk);
            per_ += __shfl_xor(per_, mk);
        }
        if (m < M) {
            #pragma unroll
            for (int nt = 0; nt < 3; ++nt) {
                int col = nt * 16 + lr;
                if (col < 40) z40[(size_t)m * 64 + col] = (__bf16)acc[nt][r];
            }
            if (lr == 0) { el3[m] = pel; er3[m] = per_; }
        }
    }
}

// ---------------------------------------------------------------------------
// edge-softmax + aggregation, layers 1-2 (H=4, F=32).
// ONE WAVE PER NODE: 4 nodes per 256-thread block. Lane t: head g=t>>4,
// elements {g*32+2j, +1} (j=t&15) -> one dword load covers 2 bf16; a wave
// instruction requests the full 256B row. Chunk = 16 edges, 16-lane-group
// parallel scores, unroll-8 gather.
// ---------------------------------------------------------------------------
__global__ __launch_bounds__(256) void gat_agg128w(
    const __bf16* __restrict__ z, const float* __restrict__ el,
    const float* __restrict__ er, const int* __restrict__ rp,
    const int* __restrict__ cs, const float* __restrict__ bias,
    __bf16* __restrict__ hout, int n_nodes)
{
    __shared__ uint2 sh[4][4][16];   // [wave][group][edge] = {row elem offset, p}
    int tid = threadIdx.x, w = tid >> 6, t = tid & 63;
    int g = t >> 4, j = t & 15;
    int nd = blockIdx.x * 4 + w;
    if (nd >= n_nodes) return;
    int beg = rp[nd], end = rp[nd + 1];
    float erv = er[nd * 4 + g];
    float m = -3.0e38f, s = 0.f, acc0 = 0.f, acc1 = 0.f;
    const int eoff = g * 32 + 2 * j;

    for (int c0 = beg; c0 < end; c0 += 16) {
        int ch = end - c0; if (ch > 16) ch = 16;
        int chp = (ch + 7) & ~7;
        // ---- phase 1: 16 edge scores per head group ----
        int sidx = (j < ch) ? cs[c0 + j] : 0;
        float e = -3.0e38f;
        if (j < ch) {
            float ev = el[sidx * 4 + g] + erv;
            e = (ev > 0.f) ? ev : 0.2f * ev;
        }
        float cm = e;
        #pragma unroll
        for (int mk = 8; mk; mk >>= 1) cm = fmaxf(cm, __shfl_xor(cm, mk));
        float nm = fmaxf(m, cm);
        float p = (j < ch) ? __expf(e - nm) : 0.f;
        float ps = p;
        #pragma unroll
        for (int mk = 8; mk; mk >>= 1) ps += __shfl_xor(ps, mk);
        float so = __expf(m - nm);
        s = s * so + ps;
        acc0 *= so; acc1 *= so;
        m = nm;
        sh[w][g][j] = make_uint2((unsigned)(sidx << 7), __float_as_uint(p));
        // intra-wave LDS: each group reads only its own row, same wave -> no barrier
        // ---- phase 2: unroll-8 dword gathers (2 bf16 each) ----
        for (int k = 0; k < chp; k += 8) {
            unsigned ld[8]; float pk[8];
            #pragma unroll
            for (int u = 0; u < 8; ++u) {
                uint2 v = sh[w][g][k + u];
                pk[u] = __uint_as_float(v.y);
                ld[u] = *reinterpret_cast<const unsigned*>(&z[(size_t)v.x + eoff]);
            }
            #pragma unroll
            for (int u = 0; u < 8; ++u) {
                float z0 = __uint_as_float(ld[u] << 16);
                float z1 = __uint_as_float(ld[u] & 0xffff0000u);
                acc0 += pk[u] * z0;
                acc1 += pk[u] * z1;
            }
        }
    }
    float o0 = (end > beg) ? acc0 / s : 0.f;
    float o1 = (end > beg) ? acc1 / s : 0.f;
    o0 = fmaxf(o0 + bias[eoff], 0.f);       // relu (layers 1-2)
    o1 = fmaxf(o1 + bias[eoff + 1], 0.f);
    __bf16 t2[2] = {(__bf16)o0, (__bf16)o1};
    *reinterpret_cast<unsigned*>(&hout[(size_t)nd * 128 + eoff]) = *reinterpret_cast<unsigned*>(t2);
}

// ---------------------------------------------------------------------------
// layer-3 aggregation: chunk-parallel, 1 node per wave, + bias + log_softmax
// ---------------------------------------------------------------------------
__global__ __launch_bounds__(256) void gat_agg40c(
    const __bf16* __restrict__ z40, const float* __restrict__ el3,
    const float* __restrict__ er3, const int* __restrict__ rp,
    const int* __restrict__ cs, const float* __restrict__ bias,
    float* __restrict__ out, int n_nodes)
{
    __shared__ uint2 sh[4][64];
    int tid = threadIdx.x, wid = tid >> 6, lane = tid & 63;
    int nd = blockIdx.x * 4 + wid;
    if (nd >= n_nodes) return;
    bool act = lane < 40;
    int beg = rp[nd], end = rp[nd + 1];
    float erv = er3[nd];
    float m = -3.0e38f, s = 0.f, acc = 0.f;

    for (int c0 = beg; c0 < end; c0 += 64) {
        int ch = end - c0; if (ch > 64) ch = 64;
        int chp = (ch + 7) & ~7;
        int sidx = (lane < ch) ? cs[c0 + lane] : 0;
        float e = -3.0e38f;
        if (lane < ch) {
            float ev = el3[sidx] + erv;
            e = (ev > 0.f) ? ev : 0.2f * ev;
        }
        float cm = e;
        #pragma unroll
        for (int mk = 32; mk; mk >>= 1) cm = fmaxf(cm, __shfl_xor(cm, mk));
        float nm = fmaxf(m, cm);
        float p = (lane < ch) ? __expf(e - nm) : 0.f;
        float ps = p;
        #pragma unroll
        for (int mk = 32; mk; mk >>= 1) ps += __shfl_xor(ps, mk);
        float so = __expf(m - nm);
        s = s * so + ps;
        acc *= so;
        m = nm;
        sh[wid][lane] = make_uint2((unsigned)(sidx << 6), __float_as_uint(p));
        for (int k = 0; k < chp; k += 8) {
            float zv[8], pk[8];
            #pragma unroll
            for (int u = 0; u < 8; ++u) {
                uint2 v = sh[wid][k + u];
                pk[u] = __uint_as_float(v.y);
                zv[u] = (float)z40[(size_t)v.x + lane];
            }
            #pragma unroll
            for (int u = 0; u < 8; ++u) acc += pk[u] * zv[u];
        }
    }
    float o = (end > beg) ? acc / s : 0.f;
    o += act ? bias[lane] : 0.f;
    float v = act ? o : -3.0e38f;
    float mx = v;
    #pragma unroll
    for (int off = 32; off > 0; off >>= 1) mx = fmaxf(mx, __shfl_xor(mx, off));
    float p2 = act ? __expf(o - mx) : 0.f;
    float sum = p2;
    #pragma unroll
    for (int off = 32; off > 0; off >>= 1) sum += __shfl_xor(sum, off);
    if (act) out[(size_t)nd * 40 + lane] = o - mx - __logf(sum);
}

// ---------------------------------------------------------------------------
extern "C" void kernel_launch(void* const* d_in, const int* in_sizes, int n_in,
                              void* d_out, int out_size, void* d_ws, size_t ws_size,
                              hipStream_t stream) {
    const float* features = (const float*)d_in[0];
    const int*   src      = (const int*)d_in[1];
    const int*   dst      = (const int*)d_in[2];
    const float* W1  = (const float*)d_in[3];
    const float* al1 = (const float*)d_in[4];
    const float* ar1 = (const float*)d_in[5];
    const float* b1  = (const float*)d_in[6];
    const float* W2  = (const float*)d_in[7];
    const float* al2 = (const float*)d_in[8];
    const float* ar2 = (const float*)d_in[9];
    const float* b2  = (const float*)d_in[10];
    const float* W3  = (const float*)d_in[11];
    const float* al3 = (const float*)d_in[12];
    const float* ar3 = (const float*)d_in[13];
    const float* b3  = (const float*)d_in[14];
    float* out = (float*)d_out;

    const int N = NNODES, E = NEDGES;
    const int NB = (N + 255) / 256;   // scan blocks = 196

    // workspace layout (bytes)
    char* ws = (char*)d_ws;
    __bf16* z40    = (__bf16*)(ws + 0);            // N*64*2 = 6,400,000 (layer 3)
    __bf16* Wt3    = (__bf16*)(ws + 6400000);      // 48*128*2 = 12,288
    __bf16* zb     = (__bf16*)(ws + 25600000);     // N*128*2
    __bf16* hb     = (__bf16*)(ws + 38400000);     // N*128*2
    float*  elb    = (float*)(ws + 51200000);      // N*4*4
    float*  erb    = (float*)(ws + 52000000);      // N*4*4
    __bf16* Wt1    = (__bf16*)(ws + 52800000);     // 128*256*2
    __bf16* Wt2    = (__bf16*)(ws + 52865536);     // 128*128*2
    int* row_ptr   = (int*)(ws + 52898304);        // (N+1)*4
    int* cursor    = (int*)(ws + 53098496);        // N*4
    int* csr_src   = (int*)(ws + 53298496);        // E*4
    int* bsum      = (int*)(ws + 56498496);        // 256*4 -> ends 56,499,520

    // ---- CSR build ----
    hipMemsetAsync(cursor, 0, (size_t)N * 4, stream);
    k_hist<<<(E + 255) / 256, 256, 0, stream>>>(dst, cursor, E);
    k_scan1<<<NB, 256, 0, stream>>>(cursor, row_ptr, bsum, N);
    k_scan2<<<1, 256, 0, stream>>>(bsum, &row_ptr[N], NB);
    k_scan3<<<NB, 256, 0, stream>>>(row_ptr, bsum, cursor, N);
    k_scatter_part<<<1024, 256, 0, stream>>>(src, dst, cursor, csr_src, E, N / NPART);

    // ---- weight converts ----
    k_wt<<<(256 * 128 + 255) / 256, 256, 0, stream>>>(W1, Wt1, 256);
    k_wt<<<(128 * 128 + 255) / 256, 256, 0, stream>>>(W2, Wt2, 128);
    k_wt3<<<(48 * 128 + 255) / 256, 256, 0, stream>>>(W3, Wt3);

    // ---- layer 1 (A = fp32 features, converted in staging) ----
    gemm_mfma_128<true><<<(N + 63) / 64, 256, 0, stream>>>(features, Wt1, al1, ar1, zb, elb, erb, N, 256);
    gat_agg128w<<<(N + 3) / 4, 256, 0, stream>>>(zb, elb, erb, row_ptr, csr_src, b1, hb, N);

    // ---- layer 2 ----
    gemm_mfma_128<false><<<(N + 63) / 64, 256, 0, stream>>>(hb, Wt2, al2, ar2, zb, elb, erb, N, 128);
    gat_agg128w<<<(N + 3) / 4, 256, 0, stream>>>(zb, elb, erb, row_ptr, csr_src, b2, hb, N);

    // ---- layer 3 ----
    gemm40_mfma<<<(N + 63) / 64, 256, 0, stream>>>(hb, Wt3, al3, ar3, z40, elb, erb, N);
    gat_agg40c<<<(N + 3) / 4, 256, 0, stream>>>(z40, elb, erb, row_ptr, csr_src, b3, out, N);

    (void)in_sizes; (void)n_in; (void)out_size; (void)ws_size;
}